// Round 7
// baseline (185.108 us; speedup 1.0000x reference)
//
#include <hip/hip_runtime.h>
#include <math.h>

namespace {

constexpr int Bn = 4, Cn = 96, Hn = 64, Wn = 64, Ln = 4096, Din = 192;
constexpr int Kn = 4, Rn = 6, Dmlp = 384;
constexpr int NCH = 128, CLEN = 32;   // 128 chunks * 32 = L

typedef short short8 __attribute__((ext_vector_type(8)));
typedef float f32x4 __attribute__((ext_vector_type(4)));

__device__ __forceinline__ float softplusf_(float x) {
  return fmaxf(x, 0.f) + __logf(1.f + __expf(-fabsf(x)));
}
__device__ __forceinline__ float siluf_(float x) {
  return x / (1.f + __expf(-x));
}
__device__ __forceinline__ float geluf_(float x) {
  return 0.5f * x * (1.f + erff(x * 0.7071067811865476f));
}
__device__ __forceinline__ unsigned short f2bf(float f) {
  unsigned u = __float_as_uint(f);
  unsigned r = 0x7fffu + ((u >> 16) & 1u);
  return (unsigned short)((u + r) >> 16);
}

// ---------------------------------------------------------------------------
// K0: zero-fill yacc (12.58 MB) with a properly-gridded float4 kernel.
// 1536 blocks x 256 thr x 2 iters of 16B = 12.58 MB.
// ---------------------------------------------------------------------------
__global__ __launch_bounds__(256) void k0_zero(float* __restrict__ p) {
  const size_t n4 = (size_t)Bn * Ln * Din / 4;   // 786432 float4s
  size_t i = (size_t)blockIdx.x * 256 + threadIdx.x;
  const float4 z = make_float4(0.f, 0.f, 0.f, 0.f);
  for (; i < n4; i += 1536 * 256)
    reinterpret_cast<float4*>(p)[i] = z;
}

// ---------------------------------------------------------------------------
// KC: convert fc1_w / fc2_w to bf16 (once per launch). 288 blocks x 256.
// ---------------------------------------------------------------------------
__global__ __launch_bounds__(256) void kc_cvt(
    const float* __restrict__ w1, const float* __restrict__ w2,
    unsigned short* __restrict__ w1b, unsigned short* __restrict__ w2b) {
  int t = blockIdx.x * 256 + threadIdx.x;
  if (t < 36864) w1b[t] = f2bf(w1[t]);
  else if (t < 73728) w2b[t - 36864] = f2bf(w2[t - 36864]);
}

// ---------------------------------------------------------------------------
// K1: LayerNorm(96) + in_proj (96->192). 32 px/block, 256 thr, grid 512.
// ---------------------------------------------------------------------------
__global__ __launch_bounds__(256) void k1_ln_inproj(
    const float* __restrict__ x, const float* __restrict__ gam,
    const float* __restrict__ bet, const float* __restrict__ W,
    float* __restrict__ ucp) {
  __shared__ float sx[32 * 97];
  const int tid = threadIdx.x;
  const int p0 = blockIdx.x * 32;
  const int b = p0 >> 12, pl0 = p0 & (Ln - 1);

  for (int f = tid; f < 32 * 96; f += 256) {
    int c = f >> 5, pp = f & 31;
    sx[pp * 97 + c] = x[((size_t)b * Cn + c) * Ln + pl0 + pp];
  }
  __syncthreads();
  {
    const int pp = tid >> 3, t8 = tid & 7;   // 8 lanes/pixel, 12 ch each
    float s = 0.f;
    for (int c = t8 * 12; c < t8 * 12 + 12; ++c) s += sx[pp * 97 + c];
    s += __shfl_xor(s, 1, 8); s += __shfl_xor(s, 2, 8); s += __shfl_xor(s, 4, 8);
    float m = s * (1.f / 96.f);
    float v = 0.f;
    for (int c = t8 * 12; c < t8 * 12 + 12; ++c) {
      float t = sx[pp * 97 + c] - m; v += t * t;
    }
    v += __shfl_xor(v, 1, 8); v += __shfl_xor(v, 2, 8); v += __shfl_xor(v, 4, 8);
    float rs = rsqrtf(v * (1.f / 96.f) + 1e-5f);
    for (int c = t8 * 12; c < t8 * 12 + 12; ++c)
      sx[pp * 97 + c] = (sx[pp * 97 + c] - m) * rs * gam[c] + bet[c];
  }
  __syncthreads();

  const int pg = tid & 7, q = tid >> 3;   // 4 px x 6 j
  float acc[4][6];
#pragma unroll
  for (int i = 0; i < 4; ++i)
#pragma unroll
    for (int j = 0; j < 6; ++j) acc[i][j] = 0.f;

  for (int c = 0; c < 96; ++c) {
    float xv[4];
#pragma unroll
    for (int i = 0; i < 4; ++i) xv[i] = sx[(4 * pg + i) * 97 + c];
#pragma unroll
    for (int j = 0; j < 6; ++j) {
      float wv = W[(q * 6 + j) * 96 + c];
#pragma unroll
      for (int i = 0; i < 4; ++i) acc[i][j] = fmaf(xv[i], wv, acc[i][j]);
    }
  }
#pragma unroll
  for (int j = 0; j < 6; ++j) {
    int jj = q * 6 + j;
    float4 v = make_float4(acc[0][j], acc[1][j], acc[2][j], acc[3][j]);
    *reinterpret_cast<float4*>(
        &ucp[((size_t)b * Din + jj) * Ln + pl0 + 4 * pg]) = v;
  }
}

// ---------------------------------------------------------------------------
// K2a: depthwise 3x3 conv + SiLU -> ut (pixel-major). Channel-split.
// ---------------------------------------------------------------------------
__global__ __launch_bounds__(512) void k2a_conv(
    const float* __restrict__ ucp, const float* __restrict__ cw,
    float* __restrict__ ut) {
  __shared__ float su[64 * 97];
  const int tid = threadIdx.x;
  const int bid = blockIdx.x;
  const int half = bid & 1, bh = bid >> 1;
  const int b = bh >> 6, h = bh & 63;
  const int w = tid & 63, wg = tid >> 6;   // 8 groups x 12 ch
  const int d0 = half * 96;

  for (int dd = 0; dd < 12; ++dd) {
    int dl = wg * 12 + dd;
    int d = d0 + dl;
    const float* base = &ucp[((size_t)b * Din + d) * Ln];
    float r0 = (h > 0) ? base[(h - 1) * 64 + w] : 0.f;
    float r1 = base[h * 64 + w];
    float r2 = (h < 63) ? base[(h + 1) * 64 + w] : 0.f;
    const float* wt = &cw[d * 9];
    float rl, rr, acc;
    rl = __shfl(r0, (w + 63) & 63); if (w == 0) rl = 0.f;
    rr = __shfl(r0, (w + 1) & 63);  if (w == 63) rr = 0.f;
    acc = rl * wt[0] + r0 * wt[1] + rr * wt[2];
    rl = __shfl(r1, (w + 63) & 63); if (w == 0) rl = 0.f;
    rr = __shfl(r1, (w + 1) & 63);  if (w == 63) rr = 0.f;
    acc += rl * wt[3] + r1 * wt[4] + rr * wt[5];
    rl = __shfl(r2, (w + 63) & 63); if (w == 0) rl = 0.f;
    rr = __shfl(r2, (w + 1) & 63);  if (w == 63) rr = 0.f;
    acc += rl * wt[6] + r2 * wt[7] + rr * wt[8];
    su[w * 97 + dl] = siluf_(acc);
  }
  __syncthreads();

  for (int f = tid; f < 64 * 96; f += 512) {
    int pp = f / 96, dl = f % 96;
    ut[((size_t)b * Ln + h * 64 + pp) * Din + d0 + dl] = su[pp * 97 + dl];
  }
}

// ---------------------------------------------------------------------------
// K2b: x_proj GEMM: dblp[p, q] = sum_d ut[p,d] * xw[q,d].
// ---------------------------------------------------------------------------
__global__ __launch_bounds__(256) void k2b_xproj(
    const float* __restrict__ ut, const float* __restrict__ xw,
    float* __restrict__ dblp) {
  __shared__ float su[32 * 193];
  __shared__ float sw[32 * 193];
  const int tid = threadIdx.x;
  const int p0 = blockIdx.x * 32;

  for (int f = tid; f < 32 * 192; f += 256) {
    int pp = f / 192, d = f % 192;
    su[pp * 193 + d] = ut[(size_t)(p0 + pp) * 192 + d];
    sw[pp * 193 + d] = xw[f];
  }
  __syncthreads();

  const int q = tid & 31, pg = tid >> 5;
  float a4[4] = {0.f, 0.f, 0.f, 0.f};
  for (int d = 0; d < 192; ++d) {
    float wv = sw[q * 193 + d];
#pragma unroll
    for (int i = 0; i < 4; ++i)
      a4[i] = fmaf(su[(4 * pg + i) * 193 + d], wv, a4[i]);
  }
#pragma unroll
  for (int i = 0; i < 4; ++i)
    dblp[(size_t)(p0 + 4 * pg + i) * 32 + q] = a4[i];
}

__device__ __forceinline__ int scan_pixel(int k, int l) {
  if (k == 0) return l;
  if (k == 1) return ((l & 63) << 6) | (l >> 6);
  if (k == 2) return Ln - 1 - l;
  int m2 = Ln - 1 - l;
  return ((m2 & 63) << 6) | (m2 >> 6);
}

// ---------------------------------------------------------------------------
// K4: scan pass 1
// ---------------------------------------------------------------------------
__global__ __launch_bounds__(192) void k4_scan1(
    const float* __restrict__ ut, const float* __restrict__ dblp,
    const float* __restrict__ wdtg, const float* __restrict__ bdtg,
    const float* __restrict__ alog, float* __restrict__ apb,
    float* __restrict__ heb) {
  const int bid = blockIdx.x;
  const int ch = bid & (NCH - 1);
  const int bk = bid / NCH;
  const int b = bk >> 2, k = bk & 3;
  const int d = threadIdx.x;

  float wdt[6];
#pragma unroll
  for (int r = 0; r < 6; ++r) wdt[r] = wdtg[(k * Din + d) * 6 + r];
  const float bdt = bdtg[k * Din + d];
  const float Av = -__expf(alog[k * Din + d]);

  const float* utb = &ut[(size_t)b * Ln * Din];
  const float* dbb = &dblp[(size_t)b * Ln * 32 + k * 8];

  float h = 0.f, ap = 1.f;
  for (int i = 0; i < CLEN; ++i) {
    int l = ch * CLEN + i;
    int p = scan_pixel(k, l);
    const float* dl = &dbb[(size_t)p * 32];
    float4 q0 = *reinterpret_cast<const float4*>(dl);
    float4 q1 = *reinterpret_cast<const float4*>(dl + 4);
    float xdt = bdt;
    xdt = fmaf(q0.x, wdt[0], xdt); xdt = fmaf(q0.y, wdt[1], xdt);
    xdt = fmaf(q0.z, wdt[2], xdt); xdt = fmaf(q0.w, wdt[3], xdt);
    xdt = fmaf(q1.x, wdt[4], xdt); xdt = fmaf(q1.y, wdt[5], xdt);
    float dt = softplusf_(xdt);
    float bs = q1.z;
    float u = utb[(size_t)p * Din + d];
    float a = __expf(dt * Av);
    float bbv = dt * bs * u;
    h = fmaf(a, h, bbv);
    ap *= a;
  }
  size_t o = ((size_t)bk * NCH + ch) * Din + d;
  apb[o] = ap;
  heb[o] = h;
}

// ---------------------------------------------------------------------------
// K5: scan pass 2 — combine chunk carries
// ---------------------------------------------------------------------------
__global__ __launch_bounds__(256) void k5_carry(
    const float* __restrict__ apb, const float* __restrict__ heb,
    float* __restrict__ cin) {
  int t = blockIdx.x * 256 + threadIdx.x;
  if (t >= Bn * Kn * Din) return;
  int bk = t / Din, d = t % Din;
  float c = 0.f;
  for (int ch = 0; ch < NCH; ++ch) {
    size_t o = ((size_t)bk * NCH + ch) * Din + d;
    cin[o] = c;
    c = fmaf(apb[o], c, heb[o]);
  }
}

// ---------------------------------------------------------------------------
// K6: scan pass 3 — recurrence with carry-in, atomic merge into yacc
// ---------------------------------------------------------------------------
__global__ __launch_bounds__(192) void k6_scan2(
    const float* __restrict__ ut, const float* __restrict__ dblp,
    const float* __restrict__ wdtg, const float* __restrict__ bdtg,
    const float* __restrict__ alog, const float* __restrict__ dsg,
    const float* __restrict__ cin, float* __restrict__ yacc) {
  const int bid = blockIdx.x;
  const int ch = bid & (NCH - 1);
  const int bk = bid / NCH;
  const int b = bk >> 2, k = bk & 3;
  const int d = threadIdx.x;

  float wdt[6];
#pragma unroll
  for (int r = 0; r < 6; ++r) wdt[r] = wdtg[(k * Din + d) * 6 + r];
  const float bdt = bdtg[k * Din + d];
  const float Av = -__expf(alog[k * Din + d]);
  const float Dv = dsg[k * Din + d];

  const float* utb = &ut[(size_t)b * Ln * Din];
  const float* dbb = &dblp[(size_t)b * Ln * 32 + k * 8];
  float* yb = &yacc[(size_t)b * Ln * Din];

  float h = cin[((size_t)bk * NCH + ch) * Din + d];
  for (int i = 0; i < CLEN; ++i) {
    int l = ch * CLEN + i;
    int p = scan_pixel(k, l);
    const float* dl = &dbb[(size_t)p * 32];
    float4 q0 = *reinterpret_cast<const float4*>(dl);
    float4 q1 = *reinterpret_cast<const float4*>(dl + 4);
    float xdt = bdt;
    xdt = fmaf(q0.x, wdt[0], xdt); xdt = fmaf(q0.y, wdt[1], xdt);
    xdt = fmaf(q0.z, wdt[2], xdt); xdt = fmaf(q0.w, wdt[3], xdt);
    xdt = fmaf(q1.x, wdt[4], xdt); xdt = fmaf(q1.y, wdt[5], xdt);
    float dt = softplusf_(xdt);
    float bs = q1.z, cs = q1.w;
    float u = utb[(size_t)p * Din + d];
    float a = __expf(dt * Av);
    float bbv = dt * bs * u;
    h = fmaf(a, h, bbv);
    float y = h * cs + Dv * u;
    atomicAdd(&yb[(size_t)p * Din + d], y);
  }
}

// ---------------------------------------------------------------------------
// K7: out_norm LN(192) + out_proj (192->96) + residual -> zt (B,L,96).
// ---------------------------------------------------------------------------
__global__ __launch_bounds__(256) void k7_outproj(
    const float* __restrict__ yacc, const float* __restrict__ gam,
    const float* __restrict__ bet, const float* __restrict__ W,
    const float* __restrict__ x, float* __restrict__ zt) {
  __shared__ float sy[32 * 193];
  const int tid = threadIdx.x;
  const int p0 = blockIdx.x * 32;
  const int b = p0 >> 12, pl0 = p0 & (Ln - 1);

  for (int f = tid; f < 32 * 192; f += 256) {
    int pp = f / 192, d = f % 192;
    sy[pp * 193 + d] = yacc[((size_t)p0 + pp) * 192 + d];
  }
  __syncthreads();
  {
    const int pp = tid >> 3, t8 = tid & 7;
    float s = 0.f;
    for (int d2 = t8 * 24; d2 < t8 * 24 + 24; ++d2) s += sy[pp * 193 + d2];
    s += __shfl_xor(s, 1, 8); s += __shfl_xor(s, 2, 8); s += __shfl_xor(s, 4, 8);
    float m = s * (1.f / 192.f);
    float v = 0.f;
    for (int d2 = t8 * 24; d2 < t8 * 24 + 24; ++d2) {
      float t = sy[pp * 193 + d2] - m; v += t * t;
    }
    v += __shfl_xor(v, 1, 8); v += __shfl_xor(v, 2, 8); v += __shfl_xor(v, 4, 8);
    float rs = rsqrtf(v * (1.f / 192.f) + 1e-5f);
    for (int d2 = t8 * 24; d2 < t8 * 24 + 24; ++d2)
      sy[pp * 193 + d2] = (sy[pp * 193 + d2] - m) * rs * gam[d2] + bet[d2];
  }
  __syncthreads();

  const int pg = tid & 7, q = tid >> 3;
  float acc[4][3];
#pragma unroll
  for (int i = 0; i < 4; ++i)
#pragma unroll
    for (int j = 0; j < 3; ++j) acc[i][j] = 0.f;

  for (int d2 = 0; d2 < Din; ++d2) {
    float yv[4];
#pragma unroll
    for (int i = 0; i < 4; ++i) yv[i] = sy[(4 * pg + i) * 193 + d2];
#pragma unroll
    for (int j = 0; j < 3; ++j) {
      float wv = W[(q * 3 + j) * Din + d2];
#pragma unroll
      for (int i = 0; i < 4; ++i) acc[i][j] = fmaf(yv[i], wv, acc[i][j]);
    }
  }
  __syncthreads();
  float* sz = sy;
#pragma unroll
  for (int j = 0; j < 3; ++j)
#pragma unroll
    for (int i = 0; i < 4; ++i) sz[(4 * pg + i) * 97 + q * 3 + j] = acc[i][j];
  __syncthreads();

  for (int f = tid; f < 32 * 96; f += 256) {
    int pp = f / 96, c = f % 96;
    zt[((size_t)p0 + pp) * 96 + c] =
        sz[pp * 97 + c] + x[((size_t)b * Cn + c) * Ln + pl0 + pp];
  }
}

// ---------------------------------------------------------------------------
// K8: MLP via bf16 MFMA. 32 px/block, 256 thr (4 waves), grid 512.
// ---------------------------------------------------------------------------
__global__ __launch_bounds__(256) void k8_mfma(
    const float* __restrict__ zt, const float* __restrict__ g2,
    const float* __restrict__ b2, const unsigned short* __restrict__ w1b,
    const float* __restrict__ b1f, const unsigned short* __restrict__ w2b,
    const float* __restrict__ b2f, const float* __restrict__ x,
    float* __restrict__ out) {
  __shared__ __align__(16) float szt[32 * 101];            // LN buf, reused for out
  __shared__ __align__(16) unsigned short sm[32 * 104];    // bf16 activations
  __shared__ __align__(16) unsigned short sh[32 * 392];    // bf16 hidden
  const int tid = threadIdx.x;
  const int p0 = blockIdx.x * 32;
  const int b = p0 >> 12, pl0 = p0 & (Ln - 1);

  for (int f = tid; f < 32 * 96; f += 256) {
    int pp = f / 96, c = f % 96;
    szt[pp * 101 + c] = zt[((size_t)p0 + pp) * 96 + c];
  }
  __syncthreads();
  {
    const int pp = tid >> 3, t8 = tid & 7;   // 8 lanes/px, 12 ch each
    float s = 0.f;
    for (int c = t8 * 12; c < t8 * 12 + 12; ++c) s += szt[pp * 101 + c];
    s += __shfl_xor(s, 1, 8); s += __shfl_xor(s, 2, 8); s += __shfl_xor(s, 4, 8);
    float m = s * (1.f / 96.f);
    float v = 0.f;
    for (int c = t8 * 12; c < t8 * 12 + 12; ++c) {
      float t = szt[pp * 101 + c] - m; v += t * t;
    }
    v += __shfl_xor(v, 1, 8); v += __shfl_xor(v, 2, 8); v += __shfl_xor(v, 4, 8);
    float rs = rsqrtf(v * (1.f / 96.f) + 1e-5f);
    for (int c = t8 * 12; c < t8 * 12 + 12; ++c)
      szt[pp * 101 + c] = (szt[pp * 101 + c] - m) * rs * g2[c] + b2[c];
  }
  __syncthreads();
  for (int f = tid; f < 32 * 96; f += 256) {
    int pp = f / 96, c = f % 96;
    sm[pp * 104 + c] = f2bf(szt[pp * 101 + c]);
  }
  __syncthreads();

  const int wv = tid >> 6;           // wave 0..3
  const int lane = tid & 63;
  const int l15 = lane & 15, lhi = lane >> 4;   // lhi 0..3

  // ---- fc1: D[px][j] = act @ w1^T. 2 m-tiles x 24 n-tiles, K=96 ----
  {
    const int mt = wv & 1;
    const int ngrp = (wv >> 1) * 12;
    for (int t = 0; t < 12; ++t) {
      const int n0 = (ngrp + t) * 16;
      f32x4 acc = {0.f, 0.f, 0.f, 0.f};
#pragma unroll
      for (int kk = 0; kk < 3; ++kk) {
        short8 av = *reinterpret_cast<const short8*>(
            &sm[(16 * mt + l15) * 104 + kk * 32 + lhi * 8]);
        short8 bv = *reinterpret_cast<const short8*>(
            &w1b[(size_t)(n0 + l15) * 96 + kk * 32 + lhi * 8]);
        acc = __builtin_amdgcn_mfma_f32_16x16x32_bf16(av, bv, acc, 0, 0, 0);
      }
      const int j = n0 + l15;
      const float bj = b1f[j];
#pragma unroll
      for (int r = 0; r < 4; ++r) {
        int px = 16 * mt + lhi * 4 + r;
        sh[px * 392 + j] = f2bf(geluf_(acc[r] + bj));
      }
    }
  }
  __syncthreads();

  // ---- fc2: D[px][c] = h @ w2^T. 12 tiles (2m x 6n), K=384 ----
  {
    for (int tt = wv; tt < 12; tt += 4) {
      const int mt = tt & 1, nt = tt >> 1;
      const int c0 = nt * 16;
      f32x4 acc = {0.f, 0.f, 0.f, 0.f};
#pragma unroll
      for (int kk = 0; kk < 12; ++kk) {
        short8 av = *reinterpret_cast<const short8*>(
            &sh[(16 * mt + l15) * 392 + kk * 32 + lhi * 8]);
        short8 bv = *reinterpret_cast<const short8*>(
            &w2b[(size_t)(c0 + l15) * 384 + kk * 32 + lhi * 8]);
        acc = __builtin_amdgcn_mfma_f32_16x16x32_bf16(av, bv, acc, 0, 0, 0);
      }
      const int c = c0 + l15;
      const float bc = b2f[c];
#pragma unroll
      for (int r = 0; r < 4; ++r) {
        int px = 16 * mt + lhi * 4 + r;
        szt[px * 101 + c] = acc[r] + bc;
      }
    }
  }
  __syncthreads();

  for (int f = tid; f < 32 * 96; f += 256) {
    int c = f >> 5, pp = f & 31;
    size_t xi = ((size_t)b * Cn + c) * Ln + pl0 + pp;
    out[xi] = x[xi] + zt[((size_t)p0 + pp) * 96 + c] + szt[pp * 101 + c];
  }
}

}  // namespace

extern "C" void kernel_launch(void* const* d_in, const int* in_sizes, int n_in,
                              void* d_out, int out_size, void* d_ws,
                              size_t ws_size, hipStream_t stream) {
  const float* x        = (const float*)d_in[0];
  const float* norm1_g  = (const float*)d_in[1];
  const float* norm1_b  = (const float*)d_in[2];
  const float* in_proj  = (const float*)d_in[3];
  const float* conv_w   = (const float*)d_in[4];
  const float* x_proj   = (const float*)d_in[5];
  const float* dt_w     = (const float*)d_in[6];
  const float* dt_b     = (const float*)d_in[7];
  const float* A_logs   = (const float*)d_in[8];
  const float* Ds       = (const float*)d_in[9];
  const float* onorm_g  = (const float*)d_in[10];
  const float* onorm_b  = (const float*)d_in[11];
  const float* out_proj = (const float*)d_in[12];
  const float* norm2_g  = (const float*)d_in[13];
  const float* norm2_b  = (const float*)d_in[14];
  const float* fc1_w    = (const float*)d_in[15];
  const float* fc1_b    = (const float*)d_in[16];
  const float* fc2_w    = (const float*)d_in[17];
  const float* fc2_b    = (const float*)d_in[18];
  float* out = (float*)d_out;

  float* ws = (float*)d_ws;
  size_t o = 0;
  float* ucp  = ws + o; o += (size_t)Bn * Din * Ln;
  float* ut   = ws + o; o += (size_t)Bn * Ln * Din;
  float* dblp = ws + o; o += (size_t)Bn * Ln * 32;
  float* apb  = ws + o; o += (size_t)Bn * Kn * NCH * Din;
  float* heb  = ws + o; o += (size_t)Bn * Kn * NCH * Din;
  float* cin  = ws + o; o += (size_t)Bn * Kn * NCH * Din;
  float* yacc = ws + o; o += (size_t)Bn * Ln * Din;
  float* zt   = ws + o; o += (size_t)Bn * Ln * Cn;
  unsigned short* w1b = (unsigned short*)(ws + o); o += 36864 / 2;
  unsigned short* w2b = (unsigned short*)(ws + o); o += 36864 / 2;

  k0_zero<<<1536, 256, 0, stream>>>(yacc);
  kc_cvt<<<288, 256, 0, stream>>>(fc1_w, fc2_w, w1b, w2b);
  k1_ln_inproj<<<512, 256, 0, stream>>>(x, norm1_g, norm1_b, in_proj, ucp);
  k2a_conv<<<Bn * Hn * 2, 512, 0, stream>>>(ucp, conv_w, ut);
  k2b_xproj<<<512, 256, 0, stream>>>(ut, x_proj, dblp);
  k4_scan1<<<Bn * Kn * NCH, 192, 0, stream>>>(ut, dblp, dt_w, dt_b, A_logs,
                                              apb, heb);
  k5_carry<<<12, 256, 0, stream>>>(apb, heb, cin);
  k6_scan2<<<Bn * Kn * NCH, 192, 0, stream>>>(ut, dblp, dt_w, dt_b, A_logs, Ds,
                                              cin, yacc);
  k7_outproj<<<512, 256, 0, stream>>>(yacc, onorm_g, onorm_b, out_proj, x, zt);
  k8_mfma<<<512, 256, 0, stream>>>(zt, norm2_g, norm2_b, w1b, fc1_b, w2b,
                                   fc2_b, x, out);
}

// Round 8
// 158.419 us; speedup vs baseline: 1.1685x; 1.1685x over previous
//
#include <hip/hip_runtime.h>
#include <math.h>

namespace {

constexpr int Bn = 4, Cn = 96, Hn = 64, Wn = 64, Ln = 4096, Din = 192;
constexpr int Kn = 4, Rn = 6, Dmlp = 384;
constexpr int NCH = 128, CLEN = 32;   // 128 chunks * 32 = L

typedef short short8 __attribute__((ext_vector_type(8)));
typedef float f32x4 __attribute__((ext_vector_type(4)));

__device__ __forceinline__ float softplusf_(float x) {
  return fmaxf(x, 0.f) + __logf(1.f + __expf(-fabsf(x)));
}
__device__ __forceinline__ float siluf_(float x) {
  return x / (1.f + __expf(-x));
}
__device__ __forceinline__ float geluf_(float x) {
  return 0.5f * x * (1.f + erff(x * 0.7071067811865476f));
}
__device__ __forceinline__ unsigned short f2bf(float f) {
  unsigned u = __float_as_uint(f);
  unsigned r = 0x7fffu + ((u >> 16) & 1u);
  return (unsigned short)((u + r) >> 16);
}

// ---------------------------------------------------------------------------
// KC: convert fc1_w / fc2_w to bf16 (once per launch). 288 blocks x 256.
// ---------------------------------------------------------------------------
__global__ __launch_bounds__(256) void kc_cvt(
    const float* __restrict__ w1, const float* __restrict__ w2,
    unsigned short* __restrict__ w1b, unsigned short* __restrict__ w2b) {
  int t = blockIdx.x * 256 + threadIdx.x;
  if (t < 36864) w1b[t] = f2bf(w1[t]);
  else if (t < 73728) w2b[t - 36864] = f2bf(w2[t - 36864]);
}

// ---------------------------------------------------------------------------
// K1: LayerNorm(96) + in_proj (96->192). 32 px/block, 256 thr, grid 512.
// ---------------------------------------------------------------------------
__global__ __launch_bounds__(256) void k1_ln_inproj(
    const float* __restrict__ x, const float* __restrict__ gam,
    const float* __restrict__ bet, const float* __restrict__ W,
    float* __restrict__ ucp) {
  __shared__ float sx[32 * 97];
  const int tid = threadIdx.x;
  const int p0 = blockIdx.x * 32;
  const int b = p0 >> 12, pl0 = p0 & (Ln - 1);

  for (int f = tid; f < 32 * 96; f += 256) {
    int c = f >> 5, pp = f & 31;
    sx[pp * 97 + c] = x[((size_t)b * Cn + c) * Ln + pl0 + pp];
  }
  __syncthreads();
  {
    const int pp = tid >> 3, t8 = tid & 7;   // 8 lanes/pixel, 12 ch each
    float s = 0.f;
    for (int c = t8 * 12; c < t8 * 12 + 12; ++c) s += sx[pp * 97 + c];
    s += __shfl_xor(s, 1, 8); s += __shfl_xor(s, 2, 8); s += __shfl_xor(s, 4, 8);
    float m = s * (1.f / 96.f);
    float v = 0.f;
    for (int c = t8 * 12; c < t8 * 12 + 12; ++c) {
      float t = sx[pp * 97 + c] - m; v += t * t;
    }
    v += __shfl_xor(v, 1, 8); v += __shfl_xor(v, 2, 8); v += __shfl_xor(v, 4, 8);
    float rs = rsqrtf(v * (1.f / 96.f) + 1e-5f);
    for (int c = t8 * 12; c < t8 * 12 + 12; ++c)
      sx[pp * 97 + c] = (sx[pp * 97 + c] - m) * rs * gam[c] + bet[c];
  }
  __syncthreads();

  const int pg = tid & 7, q = tid >> 3;   // 4 px x 6 j
  float acc[4][6];
#pragma unroll
  for (int i = 0; i < 4; ++i)
#pragma unroll
    for (int j = 0; j < 6; ++j) acc[i][j] = 0.f;

  for (int c = 0; c < 96; ++c) {
    float xv[4];
#pragma unroll
    for (int i = 0; i < 4; ++i) xv[i] = sx[(4 * pg + i) * 97 + c];
#pragma unroll
    for (int j = 0; j < 6; ++j) {
      float wv = W[(q * 6 + j) * 96 + c];
#pragma unroll
      for (int i = 0; i < 4; ++i) acc[i][j] = fmaf(xv[i], wv, acc[i][j]);
    }
  }
#pragma unroll
  for (int j = 0; j < 6; ++j) {
    int jj = q * 6 + j;
    float4 v = make_float4(acc[0][j], acc[1][j], acc[2][j], acc[3][j]);
    *reinterpret_cast<float4*>(
        &ucp[((size_t)b * Din + jj) * Ln + pl0 + 4 * pg]) = v;
  }
}

// ---------------------------------------------------------------------------
// K2a: depthwise 3x3 conv + SiLU -> ut (pixel-major). Channel-split.
// ---------------------------------------------------------------------------
__global__ __launch_bounds__(512) void k2a_conv(
    const float* __restrict__ ucp, const float* __restrict__ cw,
    float* __restrict__ ut) {
  __shared__ float su[64 * 97];
  const int tid = threadIdx.x;
  const int bid = blockIdx.x;
  const int half = bid & 1, bh = bid >> 1;
  const int b = bh >> 6, h = bh & 63;
  const int w = tid & 63, wg = tid >> 6;   // 8 groups x 12 ch
  const int d0 = half * 96;

  for (int dd = 0; dd < 12; ++dd) {
    int dl = wg * 12 + dd;
    int d = d0 + dl;
    const float* base = &ucp[((size_t)b * Din + d) * Ln];
    float r0 = (h > 0) ? base[(h - 1) * 64 + w] : 0.f;
    float r1 = base[h * 64 + w];
    float r2 = (h < 63) ? base[(h + 1) * 64 + w] : 0.f;
    const float* wt = &cw[d * 9];
    float rl, rr, acc;
    rl = __shfl(r0, (w + 63) & 63); if (w == 0) rl = 0.f;
    rr = __shfl(r0, (w + 1) & 63);  if (w == 63) rr = 0.f;
    acc = rl * wt[0] + r0 * wt[1] + rr * wt[2];
    rl = __shfl(r1, (w + 63) & 63); if (w == 0) rl = 0.f;
    rr = __shfl(r1, (w + 1) & 63);  if (w == 63) rr = 0.f;
    acc += rl * wt[3] + r1 * wt[4] + rr * wt[5];
    rl = __shfl(r2, (w + 63) & 63); if (w == 0) rl = 0.f;
    rr = __shfl(r2, (w + 1) & 63);  if (w == 63) rr = 0.f;
    acc += rl * wt[6] + r2 * wt[7] + rr * wt[8];
    su[w * 97 + dl] = siluf_(acc);
  }
  __syncthreads();

  for (int f = tid; f < 64 * 96; f += 512) {
    int pp = f / 96, dl = f % 96;
    ut[((size_t)b * Ln + h * 64 + pp) * Din + d0 + dl] = su[pp * 97 + dl];
  }
}

// ---------------------------------------------------------------------------
// K2b: x_proj GEMM: dblp[p, q] = sum_d ut[p,d] * xw[q,d].
// ---------------------------------------------------------------------------
__global__ __launch_bounds__(256) void k2b_xproj(
    const float* __restrict__ ut, const float* __restrict__ xw,
    float* __restrict__ dblp) {
  __shared__ float su[32 * 193];
  __shared__ float sw[32 * 193];
  const int tid = threadIdx.x;
  const int p0 = blockIdx.x * 32;

  for (int f = tid; f < 32 * 192; f += 256) {
    int pp = f / 192, d = f % 192;
    su[pp * 193 + d] = ut[(size_t)(p0 + pp) * 192 + d];
    sw[pp * 193 + d] = xw[f];
  }
  __syncthreads();

  const int q = tid & 31, pg = tid >> 5;
  float a4[4] = {0.f, 0.f, 0.f, 0.f};
  for (int d = 0; d < 192; ++d) {
    float wv = sw[q * 193 + d];
#pragma unroll
    for (int i = 0; i < 4; ++i)
      a4[i] = fmaf(su[(4 * pg + i) * 193 + d], wv, a4[i]);
  }
#pragma unroll
  for (int i = 0; i < 4; ++i)
    dblp[(size_t)(p0 + 4 * pg + i) * 32 + q] = a4[i];
}

__device__ __forceinline__ int scan_pixel(int k, int l) {
  if (k == 0) return l;
  if (k == 1) return ((l & 63) << 6) | (l >> 6);
  if (k == 2) return Ln - 1 - l;
  int m2 = Ln - 1 - l;
  return ((m2 & 63) << 6) | (m2 >> 6);
}

// ---------------------------------------------------------------------------
// K4: scan pass 1 — LDS-staged dblp + batch-4 ILP.
// ---------------------------------------------------------------------------
__global__ __launch_bounds__(192) void k4_scan1(
    const float* __restrict__ ut, const float* __restrict__ dblp,
    const float* __restrict__ wdtg, const float* __restrict__ bdtg,
    const float* __restrict__ alog, float* __restrict__ apb,
    float* __restrict__ heb) {
  __shared__ __align__(16) float sdb[CLEN * 8];
  const int bid = blockIdx.x;
  const int ch = bid & (NCH - 1);
  const int bk = bid / NCH;
  const int b = bk >> 2, k = bk & 3;
  const int d = threadIdx.x;
  const int l0 = ch * CLEN;

  // stage this chunk's dblp rows (32 x 8 floats, broadcast-reused by all d)
  for (int f = d; f < CLEN * 8; f += 192) {
    int i = f >> 3, c8 = f & 7;
    int p = scan_pixel(k, l0 + i);
    sdb[f] = dblp[((size_t)b * Ln + p) * 32 + k * 8 + c8];
  }

  float wdt[6];
#pragma unroll
  for (int r = 0; r < 6; ++r) wdt[r] = wdtg[(k * Din + d) * 6 + r];
  const float bdt = bdtg[k * Din + d];
  const float Av = -__expf(alog[k * Din + d]);
  const float* utb = &ut[(size_t)b * Ln * Din];
  __syncthreads();

  float h = 0.f, ap = 1.f;
  for (int i0 = 0; i0 < CLEN; i0 += 4) {
    float U[4];
#pragma unroll
    for (int j = 0; j < 4; ++j) {
      int p = scan_pixel(k, l0 + i0 + j);
      U[j] = utb[(size_t)p * Din + d];
    }
#pragma unroll
    for (int j = 0; j < 4; ++j) {
      float4 qa = *reinterpret_cast<const float4*>(&sdb[(i0 + j) * 8]);
      float4 qb = *reinterpret_cast<const float4*>(&sdb[(i0 + j) * 8 + 4]);
      float xdt = bdt;
      xdt = fmaf(qa.x, wdt[0], xdt); xdt = fmaf(qa.y, wdt[1], xdt);
      xdt = fmaf(qa.z, wdt[2], xdt); xdt = fmaf(qa.w, wdt[3], xdt);
      xdt = fmaf(qb.x, wdt[4], xdt); xdt = fmaf(qb.y, wdt[5], xdt);
      float dt = softplusf_(xdt);
      float a = __expf(dt * Av);
      float bbv = dt * qb.z * U[j];
      h = fmaf(a, h, bbv);
      ap *= a;
    }
  }
  size_t o = ((size_t)bk * NCH + ch) * Din + d;
  apb[o] = ap;
  heb[o] = h;
}

// ---------------------------------------------------------------------------
// K5: scan pass 2 — combine chunk carries
// ---------------------------------------------------------------------------
__global__ __launch_bounds__(256) void k5_carry(
    const float* __restrict__ apb, const float* __restrict__ heb,
    float* __restrict__ cin) {
  int t = blockIdx.x * 256 + threadIdx.x;
  if (t >= Bn * Kn * Din) return;
  int bk = t / Din, d = t % Din;
  float c = 0.f;
  for (int ch = 0; ch < NCH; ++ch) {
    size_t o = ((size_t)bk * NCH + ch) * Din + d;
    cin[o] = c;
    c = fmaf(apb[o], c, heb[o]);
  }
}

// ---------------------------------------------------------------------------
// K6: scan pass 3 — recurrence with carry-in; y written per-direction
// (plain coalesced stores, no atomics): yd[bk][l][d], l = scan position.
// ---------------------------------------------------------------------------
__global__ __launch_bounds__(192) void k6_scan2(
    const float* __restrict__ ut, const float* __restrict__ dblp,
    const float* __restrict__ wdtg, const float* __restrict__ bdtg,
    const float* __restrict__ alog, const float* __restrict__ dsg,
    const float* __restrict__ cin, float* __restrict__ yd) {
  __shared__ __align__(16) float sdb[CLEN * 8];
  const int bid = blockIdx.x;
  const int ch = bid & (NCH - 1);
  const int bk = bid / NCH;
  const int b = bk >> 2, k = bk & 3;
  const int d = threadIdx.x;
  const int l0 = ch * CLEN;

  for (int f = d; f < CLEN * 8; f += 192) {
    int i = f >> 3, c8 = f & 7;
    int p = scan_pixel(k, l0 + i);
    sdb[f] = dblp[((size_t)b * Ln + p) * 32 + k * 8 + c8];
  }

  float wdt[6];
#pragma unroll
  for (int r = 0; r < 6; ++r) wdt[r] = wdtg[(k * Din + d) * 6 + r];
  const float bdt = bdtg[k * Din + d];
  const float Av = -__expf(alog[k * Din + d]);
  const float Dv = dsg[k * Din + d];
  const float* utb = &ut[(size_t)b * Ln * Din];
  float* yk = &yd[(size_t)bk * Ln * Din];
  __syncthreads();

  float h = cin[((size_t)bk * NCH + ch) * Din + d];
  for (int i0 = 0; i0 < CLEN; i0 += 4) {
    float U[4];
#pragma unroll
    for (int j = 0; j < 4; ++j) {
      int p = scan_pixel(k, l0 + i0 + j);
      U[j] = utb[(size_t)p * Din + d];
    }
#pragma unroll
    for (int j = 0; j < 4; ++j) {
      float4 qa = *reinterpret_cast<const float4*>(&sdb[(i0 + j) * 8]);
      float4 qb = *reinterpret_cast<const float4*>(&sdb[(i0 + j) * 8 + 4]);
      float xdt = bdt;
      xdt = fmaf(qa.x, wdt[0], xdt); xdt = fmaf(qa.y, wdt[1], xdt);
      xdt = fmaf(qa.z, wdt[2], xdt); xdt = fmaf(qa.w, wdt[3], xdt);
      xdt = fmaf(qb.x, wdt[4], xdt); xdt = fmaf(qb.y, wdt[5], xdt);
      float dt = softplusf_(xdt);
      float a = __expf(dt * Av);
      float bbv = dt * qb.z * U[j];
      h = fmaf(a, h, bbv);
      yk[(size_t)(l0 + i0 + j) * Din + d] = h * qb.w + Dv * U[j];
    }
  }
}

// ---------------------------------------------------------------------------
// K7: merge 4 direction buffers (index-transformed) + LN(192) + out_proj
// + residual -> zt (B,L,96). 32 px/block, 256 thr, grid 512.
// ---------------------------------------------------------------------------
__global__ __launch_bounds__(256) void k7_outproj(
    const float* __restrict__ yd, const float* __restrict__ gam,
    const float* __restrict__ bet, const float* __restrict__ W,
    const float* __restrict__ x, float* __restrict__ zt) {
  __shared__ float sy[32 * 193];
  const int tid = threadIdx.x;
  const int p0 = blockIdx.x * 32;
  const int b = p0 >> 12, pl0 = p0 & (Ln - 1);

  const float* y0b = &yd[(size_t)(b * 4 + 0) * Ln * Din];
  const float* y1b = &yd[(size_t)(b * 4 + 1) * Ln * Din];
  const float* y2b = &yd[(size_t)(b * 4 + 2) * Ln * Din];
  const float* y3b = &yd[(size_t)(b * 4 + 3) * Ln * Din];

  for (int f = tid; f < 32 * 192; f += 256) {
    int pp = f / 192, d = f % 192;
    int p = pl0 + pp;                          // pixel within batch b
    int l1 = ((p & 63) << 6) | (p >> 6);       // transpose index
    float v = y0b[(size_t)p * Din + d] +
              y2b[(size_t)(Ln - 1 - p) * Din + d] +
              y1b[(size_t)l1 * Din + d] +
              y3b[(size_t)(Ln - 1 - l1) * Din + d];
    sy[pp * 193 + d] = v;
  }
  __syncthreads();
  {
    const int pp = tid >> 3, t8 = tid & 7;
    float s = 0.f;
    for (int d2 = t8 * 24; d2 < t8 * 24 + 24; ++d2) s += sy[pp * 193 + d2];
    s += __shfl_xor(s, 1, 8); s += __shfl_xor(s, 2, 8); s += __shfl_xor(s, 4, 8);
    float m = s * (1.f / 192.f);
    float v = 0.f;
    for (int d2 = t8 * 24; d2 < t8 * 24 + 24; ++d2) {
      float t = sy[pp * 193 + d2] - m; v += t * t;
    }
    v += __shfl_xor(v, 1, 8); v += __shfl_xor(v, 2, 8); v += __shfl_xor(v, 4, 8);
    float rs = rsqrtf(v * (1.f / 192.f) + 1e-5f);
    for (int d2 = t8 * 24; d2 < t8 * 24 + 24; ++d2)
      sy[pp * 193 + d2] = (sy[pp * 193 + d2] - m) * rs * gam[d2] + bet[d2];
  }
  __syncthreads();

  const int pg = tid & 7, q = tid >> 3;
  float acc[4][3];
#pragma unroll
  for (int i = 0; i < 4; ++i)
#pragma unroll
    for (int j = 0; j < 3; ++j) acc[i][j] = 0.f;

  for (int d2 = 0; d2 < Din; ++d2) {
    float yv[4];
#pragma unroll
    for (int i = 0; i < 4; ++i) yv[i] = sy[(4 * pg + i) * 193 + d2];
#pragma unroll
    for (int j = 0; j < 3; ++j) {
      float wv = W[(q * 3 + j) * Din + d2];
#pragma unroll
      for (int i = 0; i < 4; ++i) acc[i][j] = fmaf(yv[i], wv, acc[i][j]);
    }
  }
  __syncthreads();
  float* sz = sy;
#pragma unroll
  for (int j = 0; j < 3; ++j)
#pragma unroll
    for (int i = 0; i < 4; ++i) sz[(4 * pg + i) * 97 + q * 3 + j] = acc[i][j];
  __syncthreads();

  for (int f = tid; f < 32 * 96; f += 256) {
    int pp = f / 96, c = f % 96;
    zt[((size_t)p0 + pp) * 96 + c] =
        sz[pp * 97 + c] + x[((size_t)b * Cn + c) * Ln + pl0 + pp];
  }
}

// ---------------------------------------------------------------------------
// K8: MLP via bf16 MFMA. 32 px/block, 256 thr (4 waves), grid 512.
// ---------------------------------------------------------------------------
__global__ __launch_bounds__(256) void k8_mfma(
    const float* __restrict__ zt, const float* __restrict__ g2,
    const float* __restrict__ b2, const unsigned short* __restrict__ w1b,
    const float* __restrict__ b1f, const unsigned short* __restrict__ w2b,
    const float* __restrict__ b2f, const float* __restrict__ x,
    float* __restrict__ out) {
  __shared__ __align__(16) float szt[32 * 101];            // LN buf, reused for out
  __shared__ __align__(16) unsigned short sm[32 * 104];    // bf16 activations
  __shared__ __align__(16) unsigned short sh[32 * 392];    // bf16 hidden
  const int tid = threadIdx.x;
  const int p0 = blockIdx.x * 32;
  const int b = p0 >> 12, pl0 = p0 & (Ln - 1);

  for (int f = tid; f < 32 * 96; f += 256) {
    int pp = f / 96, c = f % 96;
    szt[pp * 101 + c] = zt[((size_t)p0 + pp) * 96 + c];
  }
  __syncthreads();
  {
    const int pp = tid >> 3, t8 = tid & 7;   // 8 lanes/px, 12 ch each
    float s = 0.f;
    for (int c = t8 * 12; c < t8 * 12 + 12; ++c) s += szt[pp * 101 + c];
    s += __shfl_xor(s, 1, 8); s += __shfl_xor(s, 2, 8); s += __shfl_xor(s, 4, 8);
    float m = s * (1.f / 96.f);
    float v = 0.f;
    for (int c = t8 * 12; c < t8 * 12 + 12; ++c) {
      float t = szt[pp * 101 + c] - m; v += t * t;
    }
    v += __shfl_xor(v, 1, 8); v += __shfl_xor(v, 2, 8); v += __shfl_xor(v, 4, 8);
    float rs = rsqrtf(v * (1.f / 96.f) + 1e-5f);
    for (int c = t8 * 12; c < t8 * 12 + 12; ++c)
      szt[pp * 101 + c] = (szt[pp * 101 + c] - m) * rs * g2[c] + b2[c];
  }
  __syncthreads();
  for (int f = tid; f < 32 * 96; f += 256) {
    int pp = f / 96, c = f % 96;
    sm[pp * 104 + c] = f2bf(szt[pp * 101 + c]);
  }
  __syncthreads();

  const int wv = tid >> 6;           // wave 0..3
  const int lane = tid & 63;
  const int l15 = lane & 15, lhi = lane >> 4;   // lhi 0..3

  // ---- fc1: D[px][j] = act @ w1^T. 2 m-tiles x 24 n-tiles, K=96 ----
  {
    const int mt = wv & 1;
    const int ngrp = (wv >> 1) * 12;
    for (int t = 0; t < 12; ++t) {
      const int n0 = (ngrp + t) * 16;
      f32x4 acc = {0.f, 0.f, 0.f, 0.f};
#pragma unroll
      for (int kk = 0; kk < 3; ++kk) {
        short8 av = *reinterpret_cast<const short8*>(
            &sm[(16 * mt + l15) * 104 + kk * 32 + lhi * 8]);
        short8 bv = *reinterpret_cast<const short8*>(
            &w1b[(size_t)(n0 + l15) * 96 + kk * 32 + lhi * 8]);
        acc = __builtin_amdgcn_mfma_f32_16x16x32_bf16(av, bv, acc, 0, 0, 0);
      }
      const int j = n0 + l15;
      const float bj = b1f[j];
#pragma unroll
      for (int r = 0; r < 4; ++r) {
        int px = 16 * mt + lhi * 4 + r;
        sh[px * 392 + j] = f2bf(geluf_(acc[r] + bj));
      }
    }
  }
  __syncthreads();

  // ---- fc2: D[px][c] = h @ w2^T. 12 tiles (2m x 6n), K=384 ----
  {
    for (int tt = wv; tt < 12; tt += 4) {
      const int mt = tt & 1, nt = tt >> 1;
      const int c0 = nt * 16;
      f32x4 acc = {0.f, 0.f, 0.f, 0.f};
#pragma unroll
      for (int kk = 0; kk < 12; ++kk) {
        short8 av = *reinterpret_cast<const short8*>(
            &sh[(16 * mt + l15) * 392 + kk * 32 + lhi * 8]);
        short8 bv = *reinterpret_cast<const short8*>(
            &w2b[(size_t)(c0 + l15) * 384 + kk * 32 + lhi * 8]);
        acc = __builtin_amdgcn_mfma_f32_16x16x32_bf16(av, bv, acc, 0, 0, 0);
      }
      const int c = c0 + l15;
      const float bc = b2f[c];
#pragma unroll
      for (int r = 0; r < 4; ++r) {
        int px = 16 * mt + lhi * 4 + r;
        szt[px * 101 + c] = acc[r] + bc;
      }
    }
  }
  __syncthreads();

  for (int f = tid; f < 32 * 96; f += 256) {
    int c = f >> 5, pp = f & 31;
    size_t xi = ((size_t)b * Cn + c) * Ln + pl0 + pp;
    out[xi] = x[xi] + zt[((size_t)p0 + pp) * 96 + c] + szt[pp * 101 + c];
  }
}

}  // namespace

extern "C" void kernel_launch(void* const* d_in, const int* in_sizes, int n_in,
                              void* d_out, int out_size, void* d_ws,
                              size_t ws_size, hipStream_t stream) {
  const float* x        = (const float*)d_in[0];
  const float* norm1_g  = (const float*)d_in[1];
  const float* norm1_b  = (const float*)d_in[2];
  const float* in_proj  = (const float*)d_in[3];
  const float* conv_w   = (const float*)d_in[4];
  const float* x_proj   = (const float*)d_in[5];
  const float* dt_w     = (const float*)d_in[6];
  const float* dt_b     = (const float*)d_in[7];
  const float* A_logs   = (const float*)d_in[8];
  const float* Ds       = (const float*)d_in[9];
  const float* onorm_g  = (const float*)d_in[10];
  const float* onorm_b  = (const float*)d_in[11];
  const float* out_proj = (const float*)d_in[12];
  const float* norm2_g  = (const float*)d_in[13];
  const float* norm2_b  = (const float*)d_in[14];
  const float* fc1_w    = (const float*)d_in[15];
  const float* fc1_b    = (const float*)d_in[16];
  const float* fc2_w    = (const float*)d_in[17];
  const float* fc2_b    = (const float*)d_in[18];
  float* out = (float*)d_out;

  float* ws = (float*)d_ws;
  size_t o = 0;
  float* ucp  = ws + o; o += (size_t)Bn * Din * Ln;           // 3.15M
  float* ut   = ws + o; o += (size_t)Bn * Ln * Din;           // 3.15M
  float* dblp = ws + o; o += (size_t)Bn * Ln * 32;            // 0.52M
  float* apb  = ws + o; o += (size_t)Bn * Kn * NCH * Din;
  float* heb  = ws + o; o += (size_t)Bn * Kn * NCH * Din;
  float* cin  = ws + o; o += (size_t)Bn * Kn * NCH * Din;
  float* yd   = ws + o; o += (size_t)Bn * Kn * Ln * Din;      // 12.58M (50MB)
  float* zt   = ws + o; o += (size_t)Bn * Ln * Cn;            // 1.57M
  unsigned short* w1b = (unsigned short*)(ws + o); o += 36864 / 2;
  unsigned short* w2b = (unsigned short*)(ws + o); o += 36864 / 2;

  kc_cvt<<<288, 256, 0, stream>>>(fc1_w, fc2_w, w1b, w2b);
  k1_ln_inproj<<<512, 256, 0, stream>>>(x, norm1_g, norm1_b, in_proj, ucp);
  k2a_conv<<<Bn * Hn * 2, 512, 0, stream>>>(ucp, conv_w, ut);
  k2b_xproj<<<512, 256, 0, stream>>>(ut, x_proj, dblp);
  k4_scan1<<<Bn * Kn * NCH, 192, 0, stream>>>(ut, dblp, dt_w, dt_b, A_logs,
                                              apb, heb);
  k5_carry<<<12, 256, 0, stream>>>(apb, heb, cin);
  k6_scan2<<<Bn * Kn * NCH, 192, 0, stream>>>(ut, dblp, dt_w, dt_b, A_logs, Ds,
                                              cin, yd);
  k7_outproj<<<512, 256, 0, stream>>>(yd, onorm_g, onorm_b, out_proj, x, zt);
  k8_mfma<<<512, 256, 0, stream>>>(zt, norm2_g, norm2_b, w1b, fc1_b, w2b,
                                   fc2_b, x, out);
}

// Round 9
// 131.523 us; speedup vs baseline: 1.4074x; 1.2045x over previous
//
#include <hip/hip_runtime.h>
#include <math.h>

namespace {

constexpr int Bn = 4, Cn = 96, Hn = 64, Wn = 64, Ln = 4096, Din = 192;
constexpr int Kn = 4, Rn = 6, Dmlp = 384;
constexpr int NCH = 128, CLEN = 32;   // 128 chunks * 32 = L

typedef short short8 __attribute__((ext_vector_type(8)));
typedef float f32x4 __attribute__((ext_vector_type(4)));

__device__ __forceinline__ float softplusf_(float x) {
  return fmaxf(x, 0.f) + __logf(1.f + __expf(-fabsf(x)));
}
__device__ __forceinline__ float siluf_(float x) {
  return x / (1.f + __expf(-x));
}
__device__ __forceinline__ float geluf_(float x) {
  return 0.5f * x * (1.f + erff(x * 0.7071067811865476f));
}
__device__ __forceinline__ unsigned short f2bf(float f) {
  unsigned u = __float_as_uint(f);
  unsigned r = 0x7fffu + ((u >> 16) & 1u);
  return (unsigned short)((u + r) >> 16);
}
__device__ __forceinline__ float bf2f(unsigned short v) {
  return __uint_as_float(((unsigned)v) << 16);
}

// ---------------------------------------------------------------------------
// KC: convert all weight matrices to bf16. 456 blocks x 256 = 116736 elems.
// [0,36864) fc1 | [36864,73728) fc2 | [..,92160) in_proj | [..,110592) out_proj
// | [..,116736) x_proj
// ---------------------------------------------------------------------------
__global__ __launch_bounds__(256) void kc_cvt(
    const float* __restrict__ w1, const float* __restrict__ w2,
    const float* __restrict__ win, const float* __restrict__ wout,
    const float* __restrict__ wxp,
    unsigned short* __restrict__ w1b, unsigned short* __restrict__ w2b,
    unsigned short* __restrict__ winb, unsigned short* __restrict__ woutb,
    unsigned short* __restrict__ wxpb) {
  int t = blockIdx.x * 256 + threadIdx.x;
  if (t < 36864) w1b[t] = f2bf(w1[t]);
  else if (t < 73728) w2b[t - 36864] = f2bf(w2[t - 36864]);
  else if (t < 92160) winb[t - 73728] = f2bf(win[t - 73728]);
  else if (t < 110592) woutb[t - 92160] = f2bf(wout[t - 92160]);
  else if (t < 116736) wxpb[t - 110592] = f2bf(wxp[t - 110592]);
}

// ---------------------------------------------------------------------------
// K1: LayerNorm(96) + in_proj via MFMA (96->192). 32 px/block, 256 thr.
// ---------------------------------------------------------------------------
__global__ __launch_bounds__(256) void k1_ln_inproj(
    const float* __restrict__ x, const float* __restrict__ gam,
    const float* __restrict__ bet, const unsigned short* __restrict__ winb,
    float* __restrict__ ucp) {
  __shared__ float sx[32 * 97];
  __shared__ __align__(16) unsigned short smb[32 * 104];
  const int tid = threadIdx.x;
  const int p0 = blockIdx.x * 32;
  const int b = p0 >> 12, pl0 = p0 & (Ln - 1);

  for (int f = tid; f < 32 * 96; f += 256) {
    int c = f >> 5, pp = f & 31;
    sx[pp * 97 + c] = x[((size_t)b * Cn + c) * Ln + pl0 + pp];
  }
  __syncthreads();
  {
    const int pp = tid >> 3, t8 = tid & 7;
    float s = 0.f;
    for (int c = t8 * 12; c < t8 * 12 + 12; ++c) s += sx[pp * 97 + c];
    s += __shfl_xor(s, 1, 8); s += __shfl_xor(s, 2, 8); s += __shfl_xor(s, 4, 8);
    float m = s * (1.f / 96.f);
    float v = 0.f;
    for (int c = t8 * 12; c < t8 * 12 + 12; ++c) {
      float t = sx[pp * 97 + c] - m; v += t * t;
    }
    v += __shfl_xor(v, 1, 8); v += __shfl_xor(v, 2, 8); v += __shfl_xor(v, 4, 8);
    float rs = rsqrtf(v * (1.f / 96.f) + 1e-5f);
    for (int c = t8 * 12; c < t8 * 12 + 12; ++c)
      sx[pp * 97 + c] = (sx[pp * 97 + c] - m) * rs * gam[c] + bet[c];
  }
  __syncthreads();
  for (int f = tid; f < 32 * 96; f += 256) {
    int pp = f >> 5 ? f / 96 : f / 96, c = f % 96;   // pp = f/96
    pp = f / 96;
    smb[pp * 104 + c] = f2bf(sx[pp * 97 + c]);
  }
  __syncthreads();

  const int wv = tid >> 6, lane = tid & 63;
  const int l15 = lane & 15, lhi = lane >> 4;
  const int mt = wv & 1, nbase = (wv >> 1) * 6;   // 2 m-tiles x 12 n-tiles
  for (int t = 0; t < 6; ++t) {
    const int n0 = (nbase + t) * 16;
    f32x4 acc = {0.f, 0.f, 0.f, 0.f};
#pragma unroll
    for (int kk = 0; kk < 3; ++kk) {
      short8 av = *reinterpret_cast<const short8*>(
          &smb[(16 * mt + l15) * 104 + kk * 32 + lhi * 8]);
      short8 bv = *reinterpret_cast<const short8*>(
          &winb[(size_t)(n0 + l15) * 96 + kk * 32 + lhi * 8]);
      acc = __builtin_amdgcn_mfma_f32_16x16x32_bf16(av, bv, acc, 0, 0, 0);
    }
    const int j = n0 + l15;
    float4 v = make_float4(acc[0], acc[1], acc[2], acc[3]);
    *reinterpret_cast<float4*>(
        &ucp[((size_t)b * Din + j) * Ln + pl0 + 16 * mt + lhi * 4]) = v;
  }
}

// ---------------------------------------------------------------------------
// K2a: depthwise 3x3 conv + SiLU -> ut (pixel-major, bf16). Channel-split.
// ---------------------------------------------------------------------------
__global__ __launch_bounds__(512) void k2a_conv(
    const float* __restrict__ ucp, const float* __restrict__ cw,
    unsigned short* __restrict__ utb) {
  __shared__ float su[64 * 97];
  const int tid = threadIdx.x;
  const int bid = blockIdx.x;
  const int half = bid & 1, bh = bid >> 1;
  const int b = bh >> 6, h = bh & 63;
  const int w = tid & 63, wg = tid >> 6;   // 8 groups x 12 ch
  const int d0 = half * 96;

  for (int dd = 0; dd < 12; ++dd) {
    int dl = wg * 12 + dd;
    int d = d0 + dl;
    const float* base = &ucp[((size_t)b * Din + d) * Ln];
    float r0 = (h > 0) ? base[(h - 1) * 64 + w] : 0.f;
    float r1 = base[h * 64 + w];
    float r2 = (h < 63) ? base[(h + 1) * 64 + w] : 0.f;
    const float* wt = &cw[d * 9];
    float rl, rr, acc;
    rl = __shfl(r0, (w + 63) & 63); if (w == 0) rl = 0.f;
    rr = __shfl(r0, (w + 1) & 63);  if (w == 63) rr = 0.f;
    acc = rl * wt[0] + r0 * wt[1] + rr * wt[2];
    rl = __shfl(r1, (w + 63) & 63); if (w == 0) rl = 0.f;
    rr = __shfl(r1, (w + 1) & 63);  if (w == 63) rr = 0.f;
    acc += rl * wt[3] + r1 * wt[4] + rr * wt[5];
    rl = __shfl(r2, (w + 63) & 63); if (w == 0) rl = 0.f;
    rr = __shfl(r2, (w + 1) & 63);  if (w == 63) rr = 0.f;
    acc += rl * wt[6] + r2 * wt[7] + rr * wt[8];
    su[w * 97 + dl] = siluf_(acc);
  }
  __syncthreads();

  for (int f = tid; f < 64 * 96; f += 512) {
    int pp = f / 96, dl = f % 96;
    utb[((size_t)b * Ln + h * 64 + pp) * Din + d0 + dl] =
        f2bf(su[pp * 97 + dl]);
  }
}

// ---------------------------------------------------------------------------
// K2b: x_proj via MFMA: dblp[p,q] = sum_d u[p,d]*xw[q,d]. 32px/block.
// ---------------------------------------------------------------------------
__global__ __launch_bounds__(256) void k2b_xproj(
    const unsigned short* __restrict__ utb,
    const unsigned short* __restrict__ wxpb, float* __restrict__ dblp) {
  __shared__ __align__(16) unsigned short sa[32 * 200];
  const int tid = threadIdx.x;
  const int p0 = blockIdx.x * 32;

  for (int f = tid; f < 768; f += 256) {   // 32 rows x 24 short8-chunks
    int pp = f / 24, c8 = f % 24;
    *reinterpret_cast<short8*>(&sa[pp * 200 + c8 * 8]) =
        *reinterpret_cast<const short8*>(&utb[(size_t)(p0 + pp) * 192 + c8 * 8]);
  }
  __syncthreads();

  const int wv = tid >> 6, lane = tid & 63;
  const int l15 = lane & 15, lhi = lane >> 4;
  const int mt = wv & 1, n0 = (wv >> 1) * 16;   // 2 m x 2 n tiles
  f32x4 acc = {0.f, 0.f, 0.f, 0.f};
#pragma unroll
  for (int kk = 0; kk < 6; ++kk) {
    short8 av = *reinterpret_cast<const short8*>(
        &sa[(16 * mt + l15) * 200 + kk * 32 + lhi * 8]);
    short8 bv = *reinterpret_cast<const short8*>(
        &wxpb[(size_t)(n0 + l15) * 192 + kk * 32 + lhi * 8]);
    acc = __builtin_amdgcn_mfma_f32_16x16x32_bf16(av, bv, acc, 0, 0, 0);
  }
  const int q = n0 + l15;
#pragma unroll
  for (int r = 0; r < 4; ++r) {
    int px = 16 * mt + lhi * 4 + r;
    dblp[(size_t)(p0 + px) * 32 + q] = acc[r];
  }
}

__device__ __forceinline__ int scan_pixel(int k, int l) {
  if (k == 0) return l;
  if (k == 1) return ((l & 63) << 6) | (l >> 6);
  if (k == 2) return Ln - 1 - l;
  int m2 = Ln - 1 - l;
  return ((m2 & 63) << 6) | (m2 >> 6);
}

// ---------------------------------------------------------------------------
// K4: scan pass 1 — LDS-staged dblp + batch-4 ILP, bf16 u.
// ---------------------------------------------------------------------------
__global__ __launch_bounds__(192) void k4_scan1(
    const unsigned short* __restrict__ utb, const float* __restrict__ dblp,
    const float* __restrict__ wdtg, const float* __restrict__ bdtg,
    const float* __restrict__ alog, float* __restrict__ apb,
    float* __restrict__ heb) {
  __shared__ __align__(16) float sdb[CLEN * 8];
  const int bid = blockIdx.x;
  const int ch = bid & (NCH - 1);
  const int bk = bid / NCH;
  const int b = bk >> 2, k = bk & 3;
  const int d = threadIdx.x;
  const int l0 = ch * CLEN;

  for (int f = d; f < CLEN * 8; f += 192) {
    int i = f >> 3, c8 = f & 7;
    int p = scan_pixel(k, l0 + i);
    sdb[f] = dblp[((size_t)b * Ln + p) * 32 + k * 8 + c8];
  }

  float wdt[6];
#pragma unroll
  for (int r = 0; r < 6; ++r) wdt[r] = wdtg[(k * Din + d) * 6 + r];
  const float bdt = bdtg[k * Din + d];
  const float Av = -__expf(alog[k * Din + d]);
  const unsigned short* ub = &utb[(size_t)b * Ln * Din];
  __syncthreads();

  float h = 0.f, ap = 1.f;
  for (int i0 = 0; i0 < CLEN; i0 += 4) {
    float U[4];
#pragma unroll
    for (int j = 0; j < 4; ++j) {
      int p = scan_pixel(k, l0 + i0 + j);
      U[j] = bf2f(ub[(size_t)p * Din + d]);
    }
#pragma unroll
    for (int j = 0; j < 4; ++j) {
      float4 qa = *reinterpret_cast<const float4*>(&sdb[(i0 + j) * 8]);
      float4 qb = *reinterpret_cast<const float4*>(&sdb[(i0 + j) * 8 + 4]);
      float xdt = bdt;
      xdt = fmaf(qa.x, wdt[0], xdt); xdt = fmaf(qa.y, wdt[1], xdt);
      xdt = fmaf(qa.z, wdt[2], xdt); xdt = fmaf(qa.w, wdt[3], xdt);
      xdt = fmaf(qb.x, wdt[4], xdt); xdt = fmaf(qb.y, wdt[5], xdt);
      float dt = softplusf_(xdt);
      float a = __expf(dt * Av);
      float bbv = dt * qb.z * U[j];
      h = fmaf(a, h, bbv);
      ap *= a;
    }
  }
  size_t o = ((size_t)bk * NCH + ch) * Din + d;
  apb[o] = ap;
  heb[o] = h;
}

// ---------------------------------------------------------------------------
// K5: scan pass 2 — combine chunk carries
// ---------------------------------------------------------------------------
__global__ __launch_bounds__(256) void k5_carry(
    const float* __restrict__ apb, const float* __restrict__ heb,
    float* __restrict__ cin) {
  int t = blockIdx.x * 256 + threadIdx.x;
  if (t >= Bn * Kn * Din) return;
  int bk = t / Din, d = t % Din;
  float c = 0.f;
  for (int ch = 0; ch < NCH; ++ch) {
    size_t o = ((size_t)bk * NCH + ch) * Din + d;
    cin[o] = c;
    c = fmaf(apb[o], c, heb[o]);
  }
}

// ---------------------------------------------------------------------------
// K6: scan pass 3 — recurrence with carry-in; y -> yd (bf16, per-direction).
// ---------------------------------------------------------------------------
__global__ __launch_bounds__(192) void k6_scan2(
    const unsigned short* __restrict__ utb, const float* __restrict__ dblp,
    const float* __restrict__ wdtg, const float* __restrict__ bdtg,
    const float* __restrict__ alog, const float* __restrict__ dsg,
    const float* __restrict__ cin, unsigned short* __restrict__ yd) {
  __shared__ __align__(16) float sdb[CLEN * 8];
  const int bid = blockIdx.x;
  const int ch = bid & (NCH - 1);
  const int bk = bid / NCH;
  const int b = bk >> 2, k = bk & 3;
  const int d = threadIdx.x;
  const int l0 = ch * CLEN;

  for (int f = d; f < CLEN * 8; f += 192) {
    int i = f >> 3, c8 = f & 7;
    int p = scan_pixel(k, l0 + i);
    sdb[f] = dblp[((size_t)b * Ln + p) * 32 + k * 8 + c8];
  }

  float wdt[6];
#pragma unroll
  for (int r = 0; r < 6; ++r) wdt[r] = wdtg[(k * Din + d) * 6 + r];
  const float bdt = bdtg[k * Din + d];
  const float Av = -__expf(alog[k * Din + d]);
  const float Dv = dsg[k * Din + d];
  const unsigned short* ub = &utb[(size_t)b * Ln * Din];
  unsigned short* yk = &yd[(size_t)bk * Ln * Din];
  __syncthreads();

  float h = cin[((size_t)bk * NCH + ch) * Din + d];
  for (int i0 = 0; i0 < CLEN; i0 += 4) {
    float U[4];
#pragma unroll
    for (int j = 0; j < 4; ++j) {
      int p = scan_pixel(k, l0 + i0 + j);
      U[j] = bf2f(ub[(size_t)p * Din + d]);
    }
#pragma unroll
    for (int j = 0; j < 4; ++j) {
      float4 qa = *reinterpret_cast<const float4*>(&sdb[(i0 + j) * 8]);
      float4 qb = *reinterpret_cast<const float4*>(&sdb[(i0 + j) * 8 + 4]);
      float xdt = bdt;
      xdt = fmaf(qa.x, wdt[0], xdt); xdt = fmaf(qa.y, wdt[1], xdt);
      xdt = fmaf(qa.z, wdt[2], xdt); xdt = fmaf(qa.w, wdt[3], xdt);
      xdt = fmaf(qb.x, wdt[4], xdt); xdt = fmaf(qb.y, wdt[5], xdt);
      float dt = softplusf_(xdt);
      float a = __expf(dt * Av);
      float bbv = dt * qb.z * U[j];
      h = fmaf(a, h, bbv);
      yk[(size_t)(l0 + i0 + j) * Din + d] = f2bf(h * qb.w + Dv * U[j]);
    }
  }
}

// ---------------------------------------------------------------------------
// K7: merge 4 bf16 direction buffers + LN(192) + out_proj (MFMA) + residual
// -> zt (B,L,96). 32 px/block, 256 thr.
// ---------------------------------------------------------------------------
__global__ __launch_bounds__(256) void k7_outproj(
    const unsigned short* __restrict__ yd, const float* __restrict__ gam,
    const float* __restrict__ bet, const unsigned short* __restrict__ woutb,
    const float* __restrict__ x, float* __restrict__ zt) {
  __shared__ float sy[32 * 193];
  __shared__ __align__(16) unsigned short sb7[32 * 200];
  const int tid = threadIdx.x;
  const int p0 = blockIdx.x * 32;
  const int b = p0 >> 12, pl0 = p0 & (Ln - 1);

  const unsigned short* y0b = &yd[(size_t)(b * 4 + 0) * Ln * Din];
  const unsigned short* y1b = &yd[(size_t)(b * 4 + 1) * Ln * Din];
  const unsigned short* y2b = &yd[(size_t)(b * 4 + 2) * Ln * Din];
  const unsigned short* y3b = &yd[(size_t)(b * 4 + 3) * Ln * Din];

  for (int f = tid; f < 32 * 192; f += 256) {
    int pp = f / 192, d = f % 192;
    int p = pl0 + pp;
    int l1 = ((p & 63) << 6) | (p >> 6);
    float v = bf2f(y0b[(size_t)p * Din + d]) +
              bf2f(y2b[(size_t)(Ln - 1 - p) * Din + d]) +
              bf2f(y1b[(size_t)l1 * Din + d]) +
              bf2f(y3b[(size_t)(Ln - 1 - l1) * Din + d]);
    sy[pp * 193 + d] = v;
  }
  __syncthreads();
  {
    const int pp = tid >> 3, t8 = tid & 7;
    float s = 0.f;
    for (int d2 = t8 * 24; d2 < t8 * 24 + 24; ++d2) s += sy[pp * 193 + d2];
    s += __shfl_xor(s, 1, 8); s += __shfl_xor(s, 2, 8); s += __shfl_xor(s, 4, 8);
    float m = s * (1.f / 192.f);
    float v = 0.f;
    for (int d2 = t8 * 24; d2 < t8 * 24 + 24; ++d2) {
      float t = sy[pp * 193 + d2] - m; v += t * t;
    }
    v += __shfl_xor(v, 1, 8); v += __shfl_xor(v, 2, 8); v += __shfl_xor(v, 4, 8);
    float rs = rsqrtf(v * (1.f / 192.f) + 1e-5f);
    for (int d2 = t8 * 24; d2 < t8 * 24 + 24; ++d2)
      sb7[pp * 200 + d2] =
          f2bf((sy[pp * 193 + d2] - m) * rs * gam[d2] + bet[d2]);
  }
  __syncthreads();

  const int wv = tid >> 6, lane = tid & 63;
  const int l15 = lane & 15, lhi = lane >> 4;
  float* sz = sy;   // reuse sy as [32][97] output staging
  for (int tt = wv; tt < 12; tt += 4) {   // 2 m x 6 n tiles
    const int mt = tt & 1, c0 = (tt >> 1) * 16;
    f32x4 acc = {0.f, 0.f, 0.f, 0.f};
#pragma unroll
    for (int kk = 0; kk < 6; ++kk) {
      short8 av = *reinterpret_cast<const short8*>(
          &sb7[(16 * mt + l15) * 200 + kk * 32 + lhi * 8]);
      short8 bv = *reinterpret_cast<const short8*>(
          &woutb[(size_t)(c0 + l15) * 192 + kk * 32 + lhi * 8]);
      acc = __builtin_amdgcn_mfma_f32_16x16x32_bf16(av, bv, acc, 0, 0, 0);
    }
    const int c = c0 + l15;
#pragma unroll
    for (int r = 0; r < 4; ++r) {
      int px = 16 * mt + lhi * 4 + r;
      sz[px * 97 + c] = acc[r];
    }
  }
  __syncthreads();

  for (int f = tid; f < 32 * 96; f += 256) {
    int pp = f / 96, c = f % 96;
    zt[((size_t)p0 + pp) * 96 + c] =
        sz[pp * 97 + c] + x[((size_t)b * Cn + c) * Ln + pl0 + pp];
  }
}

// ---------------------------------------------------------------------------
// K8: MLP via bf16 MFMA. 32 px/block, 256 thr (4 waves), grid 512.
// ---------------------------------------------------------------------------
__global__ __launch_bounds__(256) void k8_mfma(
    const float* __restrict__ zt, const float* __restrict__ g2,
    const float* __restrict__ b2, const unsigned short* __restrict__ w1b,
    const float* __restrict__ b1f, const unsigned short* __restrict__ w2b,
    const float* __restrict__ b2f, const float* __restrict__ x,
    float* __restrict__ out) {
  __shared__ __align__(16) float szt[32 * 101];
  __shared__ __align__(16) unsigned short sm[32 * 104];
  __shared__ __align__(16) unsigned short sh[32 * 392];
  const int tid = threadIdx.x;
  const int p0 = blockIdx.x * 32;
  const int b = p0 >> 12, pl0 = p0 & (Ln - 1);

  for (int f = tid; f < 32 * 96; f += 256) {
    int pp = f / 96, c = f % 96;
    szt[pp * 101 + c] = zt[((size_t)p0 + pp) * 96 + c];
  }
  __syncthreads();
  {
    const int pp = tid >> 3, t8 = tid & 7;
    float s = 0.f;
    for (int c = t8 * 12; c < t8 * 12 + 12; ++c) s += szt[pp * 101 + c];
    s += __shfl_xor(s, 1, 8); s += __shfl_xor(s, 2, 8); s += __shfl_xor(s, 4, 8);
    float m = s * (1.f / 96.f);
    float v = 0.f;
    for (int c = t8 * 12; c < t8 * 12 + 12; ++c) {
      float t = szt[pp * 101 + c] - m; v += t * t;
    }
    v += __shfl_xor(v, 1, 8); v += __shfl_xor(v, 2, 8); v += __shfl_xor(v, 4, 8);
    float rs = rsqrtf(v * (1.f / 96.f) + 1e-5f);
    for (int c = t8 * 12; c < t8 * 12 + 12; ++c)
      sm[pp * 104 + c] = f2bf((szt[pp * 101 + c] - m) * rs * g2[c] + b2[c]);
  }
  __syncthreads();

  const int wv = tid >> 6;
  const int lane = tid & 63;
  const int l15 = lane & 15, lhi = lane >> 4;

  // fc1: 2 m x 24 n tiles, K=96
  {
    const int mt = wv & 1;
    const int ngrp = (wv >> 1) * 12;
    for (int t = 0; t < 12; ++t) {
      const int n0 = (ngrp + t) * 16;
      f32x4 acc = {0.f, 0.f, 0.f, 0.f};
#pragma unroll
      for (int kk = 0; kk < 3; ++kk) {
        short8 av = *reinterpret_cast<const short8*>(
            &sm[(16 * mt + l15) * 104 + kk * 32 + lhi * 8]);
        short8 bv = *reinterpret_cast<const short8*>(
            &w1b[(size_t)(n0 + l15) * 96 + kk * 32 + lhi * 8]);
        acc = __builtin_amdgcn_mfma_f32_16x16x32_bf16(av, bv, acc, 0, 0, 0);
      }
      const int j = n0 + l15;
      const float bj = b1f[j];
#pragma unroll
      for (int r = 0; r < 4; ++r) {
        int px = 16 * mt + lhi * 4 + r;
        sh[px * 392 + j] = f2bf(geluf_(acc[r] + bj));
      }
    }
  }
  __syncthreads();

  // fc2: 12 tiles (2m x 6n), K=384
  {
    for (int tt = wv; tt < 12; tt += 4) {
      const int mt = tt & 1, nt = tt >> 1;
      const int c0 = nt * 16;
      f32x4 acc = {0.f, 0.f, 0.f, 0.f};
#pragma unroll
      for (int kk = 0; kk < 12; ++kk) {
        short8 av = *reinterpret_cast<const short8*>(
            &sh[(16 * mt + l15) * 392 + kk * 32 + lhi * 8]);
        short8 bv = *reinterpret_cast<const short8*>(
            &w2b[(size_t)(c0 + l15) * 384 + kk * 32 + lhi * 8]);
        acc = __builtin_amdgcn_mfma_f32_16x16x32_bf16(av, bv, acc, 0, 0, 0);
      }
      const int c = c0 + l15;
      const float bc = b2f[c];
#pragma unroll
      for (int r = 0; r < 4; ++r) {
        int px = 16 * mt + lhi * 4 + r;
        szt[px * 101 + c] = acc[r] + bc;
      }
    }
  }
  __syncthreads();

  for (int f = tid; f < 32 * 96; f += 256) {
    int c = f >> 5, pp = f & 31;
    size_t xi = ((size_t)b * Cn + c) * Ln + pl0 + pp;
    out[xi] = x[xi] + zt[((size_t)p0 + pp) * 96 + c] + szt[pp * 101 + c];
  }
}

}  // namespace

extern "C" void kernel_launch(void* const* d_in, const int* in_sizes, int n_in,
                              void* d_out, int out_size, void* d_ws,
                              size_t ws_size, hipStream_t stream) {
  const float* x        = (const float*)d_in[0];
  const float* norm1_g  = (const float*)d_in[1];
  const float* norm1_b  = (const float*)d_in[2];
  const float* in_proj  = (const float*)d_in[3];
  const float* conv_w   = (const float*)d_in[4];
  const float* x_proj   = (const float*)d_in[5];
  const float* dt_w     = (const float*)d_in[6];
  const float* dt_b     = (const float*)d_in[7];
  const float* A_logs   = (const float*)d_in[8];
  const float* Ds       = (const float*)d_in[9];
  const float* onorm_g  = (const float*)d_in[10];
  const float* onorm_b  = (const float*)d_in[11];
  const float* out_proj = (const float*)d_in[12];
  const float* norm2_g  = (const float*)d_in[13];
  const float* norm2_b  = (const float*)d_in[14];
  const float* fc1_w    = (const float*)d_in[15];
  const float* fc1_b    = (const float*)d_in[16];
  const float* fc2_w    = (const float*)d_in[17];
  const float* fc2_b    = (const float*)d_in[18];
  float* out = (float*)d_out;

  float* ws = (float*)d_ws;
  size_t o = 0;
  float* ucp  = ws + o; o += (size_t)Bn * Din * Ln;              // f32 12.6MB
  float* dblp = ws + o; o += (size_t)Bn * Ln * 32;               // f32 2.1MB
  float* apb  = ws + o; o += (size_t)Bn * Kn * NCH * Din;
  float* heb  = ws + o; o += (size_t)Bn * Kn * NCH * Din;
  float* cin  = ws + o; o += (size_t)Bn * Kn * NCH * Din;
  float* zt   = ws + o; o += (size_t)Bn * Ln * Cn;               // f32 6.3MB
  unsigned short* utb = (unsigned short*)(ws + o); o += (size_t)Bn * Ln * Din / 2;      // bf16 6.3MB
  unsigned short* yd  = (unsigned short*)(ws + o); o += (size_t)Bn * Kn * Ln * Din / 2; // bf16 25MB
  unsigned short* w1b = (unsigned short*)(ws + o); o += 36864 / 2;
  unsigned short* w2b = (unsigned short*)(ws + o); o += 36864 / 2;
  unsigned short* winb = (unsigned short*)(ws + o); o += 18432 / 2;
  unsigned short* woutb = (unsigned short*)(ws + o); o += 18432 / 2;
  unsigned short* wxpb = (unsigned short*)(ws + o); o += 6144 / 2;

  kc_cvt<<<456, 256, 0, stream>>>(fc1_w, fc2_w, in_proj, out_proj, x_proj,
                                  w1b, w2b, winb, woutb, wxpb);
  k1_ln_inproj<<<512, 256, 0, stream>>>(x, norm1_g, norm1_b, winb, ucp);
  k2a_conv<<<Bn * Hn * 2, 512, 0, stream>>>(ucp, conv_w, utb);
  k2b_xproj<<<512, 256, 0, stream>>>(utb, wxpb, dblp);
  k4_scan1<<<Bn * Kn * NCH, 192, 0, stream>>>(utb, dblp, dt_w, dt_b, A_logs,
                                              apb, heb);
  k5_carry<<<12, 256, 0, stream>>>(apb, heb, cin);
  k6_scan2<<<Bn * Kn * NCH, 192, 0, stream>>>(utb, dblp, dt_w, dt_b, A_logs,
                                              Ds, cin, yd);
  k7_outproj<<<512, 256, 0, stream>>>(yd, onorm_g, onorm_b, woutb, x, zt);
  k8_mfma<<<512, 256, 0, stream>>>(zt, norm2_g, norm2_b, w1b, fc1_b, w2b,
                                   fc2_b, x, out);
}

// Round 10
// 126.790 us; speedup vs baseline: 1.4600x; 1.0373x over previous
//
#include <hip/hip_runtime.h>
#include <math.h>

namespace {

constexpr int Bn = 4, Cn = 96, Hn = 64, Wn = 64, Ln = 4096, Din = 192;
constexpr int Kn = 4, Rn = 6, Dmlp = 384;
constexpr int NCH = 128, CLEN = 32;   // 128 chunks * 32 = L

typedef short short8 __attribute__((ext_vector_type(8)));
typedef float f32x4 __attribute__((ext_vector_type(4)));

__device__ __forceinline__ float softplusf_(float x) {
  return fmaxf(x, 0.f) + __logf(1.f + __expf(-fabsf(x)));
}
__device__ __forceinline__ float siluf_(float x) {
  return x / (1.f + __expf(-x));
}
__device__ __forceinline__ float geluf_(float x) {
  return 0.5f * x * (1.f + erff(x * 0.7071067811865476f));
}
__device__ __forceinline__ unsigned short f2bf(float f) {
  unsigned u = __float_as_uint(f);
  unsigned r = 0x7fffu + ((u >> 16) & 1u);
  return (unsigned short)((u + r) >> 16);
}
__device__ __forceinline__ float bf2f(unsigned short v) {
  return __uint_as_float(((unsigned)v) << 16);
}

// ---------------------------------------------------------------------------
// KC: convert all weight matrices to bf16. 456 blocks x 256 = 116736 elems.
// ---------------------------------------------------------------------------
__global__ __launch_bounds__(256) void kc_cvt(
    const float* __restrict__ w1, const float* __restrict__ w2,
    const float* __restrict__ win, const float* __restrict__ wout,
    const float* __restrict__ wxp,
    unsigned short* __restrict__ w1b, unsigned short* __restrict__ w2b,
    unsigned short* __restrict__ winb, unsigned short* __restrict__ woutb,
    unsigned short* __restrict__ wxpb) {
  int t = blockIdx.x * 256 + threadIdx.x;
  if (t < 36864) w1b[t] = f2bf(w1[t]);
  else if (t < 73728) w2b[t - 36864] = f2bf(w2[t - 36864]);
  else if (t < 92160) winb[t - 73728] = f2bf(win[t - 73728]);
  else if (t < 110592) woutb[t - 92160] = f2bf(wout[t - 92160]);
  else if (t < 116736) wxpb[t - 110592] = f2bf(wxp[t - 110592]);
}

// ---------------------------------------------------------------------------
// K1: LayerNorm(96) + in_proj via MFMA (96->192) -> ucp (bf16, channel-planar)
// ---------------------------------------------------------------------------
__global__ __launch_bounds__(256) void k1_ln_inproj(
    const float* __restrict__ x, const float* __restrict__ gam,
    const float* __restrict__ bet, const unsigned short* __restrict__ winb,
    unsigned short* __restrict__ ucpb) {
  __shared__ float sx[32 * 97];
  __shared__ __align__(16) unsigned short smb[32 * 104];
  const int tid = threadIdx.x;
  const int p0 = blockIdx.x * 32;
  const int b = p0 >> 12, pl0 = p0 & (Ln - 1);

  for (int f = tid; f < 32 * 96; f += 256) {
    int c = f >> 5, pp = f & 31;
    sx[pp * 97 + c] = x[((size_t)b * Cn + c) * Ln + pl0 + pp];
  }
  __syncthreads();
  {
    const int pp = tid >> 3, t8 = tid & 7;
    float s = 0.f;
    for (int c = t8 * 12; c < t8 * 12 + 12; ++c) s += sx[pp * 97 + c];
    s += __shfl_xor(s, 1, 8); s += __shfl_xor(s, 2, 8); s += __shfl_xor(s, 4, 8);
    float m = s * (1.f / 96.f);
    float v = 0.f;
    for (int c = t8 * 12; c < t8 * 12 + 12; ++c) {
      float t = sx[pp * 97 + c] - m; v += t * t;
    }
    v += __shfl_xor(v, 1, 8); v += __shfl_xor(v, 2, 8); v += __shfl_xor(v, 4, 8);
    float rs = rsqrtf(v * (1.f / 96.f) + 1e-5f);
    for (int c = t8 * 12; c < t8 * 12 + 12; ++c)
      sx[pp * 97 + c] = (sx[pp * 97 + c] - m) * rs * gam[c] + bet[c];
  }
  __syncthreads();
  for (int f = tid; f < 32 * 96; f += 256) {
    int pp = f / 96, c = f % 96;
    smb[pp * 104 + c] = f2bf(sx[pp * 97 + c]);
  }
  __syncthreads();

  const int wv = tid >> 6, lane = tid & 63;
  const int l15 = lane & 15, lhi = lane >> 4;
  const int mt = wv & 1, nbase = (wv >> 1) * 6;   // 2 m-tiles x 12 n-tiles
  for (int t = 0; t < 6; ++t) {
    const int n0 = (nbase + t) * 16;
    f32x4 acc = {0.f, 0.f, 0.f, 0.f};
#pragma unroll
    for (int kk = 0; kk < 3; ++kk) {
      short8 av = *reinterpret_cast<const short8*>(
          &smb[(16 * mt + l15) * 104 + kk * 32 + lhi * 8]);
      short8 bv = *reinterpret_cast<const short8*>(
          &winb[(size_t)(n0 + l15) * 96 + kk * 32 + lhi * 8]);
      acc = __builtin_amdgcn_mfma_f32_16x16x32_bf16(av, bv, acc, 0, 0, 0);
    }
    const int j = n0 + l15;
    uint2 pk;
    pk.x = (unsigned)f2bf(acc[0]) | ((unsigned)f2bf(acc[1]) << 16);
    pk.y = (unsigned)f2bf(acc[2]) | ((unsigned)f2bf(acc[3]) << 16);
    *reinterpret_cast<uint2*>(
        &ucpb[((size_t)b * Din + j) * Ln + pl0 + 16 * mt + lhi * 4]) = pk;
  }
}

// ---------------------------------------------------------------------------
// K2a: depthwise 3x3 conv + SiLU -> utb (pixel-major bf16). Channel-split.
// ---------------------------------------------------------------------------
__global__ __launch_bounds__(512) void k2a_conv(
    const unsigned short* __restrict__ ucpb, const float* __restrict__ cw,
    unsigned short* __restrict__ utb) {
  __shared__ float su[64 * 97];
  const int tid = threadIdx.x;
  const int bid = blockIdx.x;
  const int half = bid & 1, bh = bid >> 1;
  const int b = bh >> 6, h = bh & 63;
  const int w = tid & 63, wg = tid >> 6;   // 8 groups x 12 ch
  const int d0 = half * 96;

  for (int dd = 0; dd < 12; ++dd) {
    int dl = wg * 12 + dd;
    int d = d0 + dl;
    const unsigned short* base = &ucpb[((size_t)b * Din + d) * Ln];
    float r0 = (h > 0) ? bf2f(base[(h - 1) * 64 + w]) : 0.f;
    float r1 = bf2f(base[h * 64 + w]);
    float r2 = (h < 63) ? bf2f(base[(h + 1) * 64 + w]) : 0.f;
    const float* wt = &cw[d * 9];
    float rl, rr, acc;
    rl = __shfl(r0, (w + 63) & 63); if (w == 0) rl = 0.f;
    rr = __shfl(r0, (w + 1) & 63);  if (w == 63) rr = 0.f;
    acc = rl * wt[0] + r0 * wt[1] + rr * wt[2];
    rl = __shfl(r1, (w + 63) & 63); if (w == 0) rl = 0.f;
    rr = __shfl(r1, (w + 1) & 63);  if (w == 63) rr = 0.f;
    acc += rl * wt[3] + r1 * wt[4] + rr * wt[5];
    rl = __shfl(r2, (w + 63) & 63); if (w == 0) rl = 0.f;
    rr = __shfl(r2, (w + 1) & 63);  if (w == 63) rr = 0.f;
    acc += rl * wt[6] + r2 * wt[7] + rr * wt[8];
    su[w * 97 + dl] = siluf_(acc);
  }
  __syncthreads();

  for (int f = tid; f < 64 * 96; f += 512) {
    int pp = f / 96, dl = f % 96;
    utb[((size_t)b * Ln + h * 64 + pp) * Din + d0 + dl] =
        f2bf(su[pp * 97 + dl]);
  }
}

// ---------------------------------------------------------------------------
// K2b: x_proj via MFMA: dblp[p,q] = sum_d u[p,d]*xw[q,d]. 32px/block.
// ---------------------------------------------------------------------------
__global__ __launch_bounds__(256) void k2b_xproj(
    const unsigned short* __restrict__ utb,
    const unsigned short* __restrict__ wxpb, float* __restrict__ dblp) {
  __shared__ __align__(16) unsigned short sa[32 * 200];
  const int tid = threadIdx.x;
  const int p0 = blockIdx.x * 32;

  for (int f = tid; f < 768; f += 256) {   // 32 rows x 24 short8-chunks
    int pp = f / 24, c8 = f % 24;
    *reinterpret_cast<short8*>(&sa[pp * 200 + c8 * 8]) =
        *reinterpret_cast<const short8*>(&utb[(size_t)(p0 + pp) * 192 + c8 * 8]);
  }
  __syncthreads();

  const int wv = tid >> 6, lane = tid & 63;
  const int l15 = lane & 15, lhi = lane >> 4;
  const int mt = wv & 1, n0 = (wv >> 1) * 16;   // 2 m x 2 n tiles
  f32x4 acc = {0.f, 0.f, 0.f, 0.f};
#pragma unroll
  for (int kk = 0; kk < 6; ++kk) {
    short8 av = *reinterpret_cast<const short8*>(
        &sa[(16 * mt + l15) * 200 + kk * 32 + lhi * 8]);
    short8 bv = *reinterpret_cast<const short8*>(
        &wxpb[(size_t)(n0 + l15) * 192 + kk * 32 + lhi * 8]);
    acc = __builtin_amdgcn_mfma_f32_16x16x32_bf16(av, bv, acc, 0, 0, 0);
  }
  const int q = n0 + l15;
#pragma unroll
  for (int r = 0; r < 4; ++r) {
    int px = 16 * mt + lhi * 4 + r;
    dblp[(size_t)(p0 + px) * 32 + q] = acc[r];
  }
}

__device__ __forceinline__ int scan_pixel(int k, int l) {
  if (k == 0) return l;
  if (k == 1) return ((l & 63) << 6) | (l >> 6);
  if (k == 2) return Ln - 1 - l;
  int m2 = Ln - 1 - l;
  return ((m2 & 63) << 6) | (m2 >> 6);
}

// ---------------------------------------------------------------------------
// K4: scan pass 1 — LDS-staged dblp + batch-8 ILP, bf16 u.
// ---------------------------------------------------------------------------
__global__ __launch_bounds__(192) void k4_scan1(
    const unsigned short* __restrict__ utb, const float* __restrict__ dblp,
    const float* __restrict__ wdtg, const float* __restrict__ bdtg,
    const float* __restrict__ alog, float* __restrict__ apb,
    float* __restrict__ heb) {
  __shared__ __align__(16) float sdb[CLEN * 8];
  const int bid = blockIdx.x;
  const int ch = bid & (NCH - 1);
  const int bk = bid / NCH;
  const int b = bk >> 2, k = bk & 3;
  const int d = threadIdx.x;
  const int l0 = ch * CLEN;

  for (int f = d; f < CLEN * 8; f += 192) {
    int i = f >> 3, c8 = f & 7;
    int p = scan_pixel(k, l0 + i);
    sdb[f] = dblp[((size_t)b * Ln + p) * 32 + k * 8 + c8];
  }

  float wdt[6];
#pragma unroll
  for (int r = 0; r < 6; ++r) wdt[r] = wdtg[(k * Din + d) * 6 + r];
  const float bdt = bdtg[k * Din + d];
  const float Av = -__expf(alog[k * Din + d]);
  const unsigned short* ub = &utb[(size_t)b * Ln * Din];
  __syncthreads();

  float h = 0.f, ap = 1.f;
  for (int i0 = 0; i0 < CLEN; i0 += 8) {
    float U[8];
#pragma unroll
    for (int j = 0; j < 8; ++j) {
      int p = scan_pixel(k, l0 + i0 + j);
      U[j] = bf2f(ub[(size_t)p * Din + d]);
    }
#pragma unroll
    for (int j = 0; j < 8; ++j) {
      float4 qa = *reinterpret_cast<const float4*>(&sdb[(i0 + j) * 8]);
      float4 qb = *reinterpret_cast<const float4*>(&sdb[(i0 + j) * 8 + 4]);
      float xdt = bdt;
      xdt = fmaf(qa.x, wdt[0], xdt); xdt = fmaf(qa.y, wdt[1], xdt);
      xdt = fmaf(qa.z, wdt[2], xdt); xdt = fmaf(qa.w, wdt[3], xdt);
      xdt = fmaf(qb.x, wdt[4], xdt); xdt = fmaf(qb.y, wdt[5], xdt);
      float dt = softplusf_(xdt);
      float a = __expf(dt * Av);
      float bbv = dt * qb.z * U[j];
      h = fmaf(a, h, bbv);
      ap *= a;
    }
  }
  size_t o = ((size_t)bk * NCH + ch) * Din + d;
  apb[o] = ap;
  heb[o] = h;
}

// ---------------------------------------------------------------------------
// K5: scan pass 2 — combine chunk carries
// ---------------------------------------------------------------------------
__global__ __launch_bounds__(256) void k5_carry(
    const float* __restrict__ apb, const float* __restrict__ heb,
    float* __restrict__ cin) {
  int t = blockIdx.x * 256 + threadIdx.x;
  if (t >= Bn * Kn * Din) return;
  int bk = t / Din, d = t % Din;
  float c = 0.f;
  for (int ch = 0; ch < NCH; ++ch) {
    size_t o = ((size_t)bk * NCH + ch) * Din + d;
    cin[o] = c;
    c = fmaf(apb[o], c, heb[o]);
  }
}

// ---------------------------------------------------------------------------
// K6: scan pass 3 — recurrence with carry-in; y -> yd (bf16, per-direction).
// ---------------------------------------------------------------------------
__global__ __launch_bounds__(192) void k6_scan2(
    const unsigned short* __restrict__ utb, const float* __restrict__ dblp,
    const float* __restrict__ wdtg, const float* __restrict__ bdtg,
    const float* __restrict__ alog, const float* __restrict__ dsg,
    const float* __restrict__ cin, unsigned short* __restrict__ yd) {
  __shared__ __align__(16) float sdb[CLEN * 8];
  const int bid = blockIdx.x;
  const int ch = bid & (NCH - 1);
  const int bk = bid / NCH;
  const int b = bk >> 2, k = bk & 3;
  const int d = threadIdx.x;
  const int l0 = ch * CLEN;

  for (int f = d; f < CLEN * 8; f += 192) {
    int i = f >> 3, c8 = f & 7;
    int p = scan_pixel(k, l0 + i);
    sdb[f] = dblp[((size_t)b * Ln + p) * 32 + k * 8 + c8];
  }

  float wdt[6];
#pragma unroll
  for (int r = 0; r < 6; ++r) wdt[r] = wdtg[(k * Din + d) * 6 + r];
  const float bdt = bdtg[k * Din + d];
  const float Av = -__expf(alog[k * Din + d]);
  const float Dv = dsg[k * Din + d];
  const unsigned short* ub = &utb[(size_t)b * Ln * Din];
  unsigned short* yk = &yd[(size_t)bk * Ln * Din];
  __syncthreads();

  float h = cin[((size_t)bk * NCH + ch) * Din + d];
  for (int i0 = 0; i0 < CLEN; i0 += 8) {
    float U[8];
#pragma unroll
    for (int j = 0; j < 8; ++j) {
      int p = scan_pixel(k, l0 + i0 + j);
      U[j] = bf2f(ub[(size_t)p * Din + d]);
    }
#pragma unroll
    for (int j = 0; j < 8; ++j) {
      float4 qa = *reinterpret_cast<const float4*>(&sdb[(i0 + j) * 8]);
      float4 qb = *reinterpret_cast<const float4*>(&sdb[(i0 + j) * 8 + 4]);
      float xdt = bdt;
      xdt = fmaf(qa.x, wdt[0], xdt); xdt = fmaf(qa.y, wdt[1], xdt);
      xdt = fmaf(qa.z, wdt[2], xdt); xdt = fmaf(qa.w, wdt[3], xdt);
      xdt = fmaf(qb.x, wdt[4], xdt); xdt = fmaf(qb.y, wdt[5], xdt);
      float dt = softplusf_(xdt);
      float a = __expf(dt * Av);
      float bbv = dt * qb.z * U[j];
      h = fmaf(a, h, bbv);
      yk[(size_t)(l0 + i0 + j) * Din + d] = f2bf(h * qb.w + Dv * U[j]);
    }
  }
}

// ---------------------------------------------------------------------------
// K78: fused tail — merge yd + LN(192) + out_proj MFMA + residual (z in LDS)
//      + LN(96) + fc1 MFMA + gelu + fc2 MFMA + final out. 32px/block.
// LDS union (62.6KB): [0,24704) SY f32[32][193] -> later SZ f32[32][97] @0 +
// SM bf16[32][104] @12416 ; [24704,37504) SB7 bf16[32][200] -> later SMLP
// f32[32][97] ; [37504,62592) SH bf16[32][392].
// ---------------------------------------------------------------------------
__global__ __launch_bounds__(256) void k78_tail(
    const unsigned short* __restrict__ yd, const float* __restrict__ gam,
    const float* __restrict__ bet, const unsigned short* __restrict__ woutb,
    const float* __restrict__ g2, const float* __restrict__ b2,
    const unsigned short* __restrict__ w1b, const float* __restrict__ b1f,
    const unsigned short* __restrict__ w2b, const float* __restrict__ b2f,
    const float* __restrict__ x, float* __restrict__ out) {
  __shared__ __align__(16) char smem[62592];
  float* SY = (float*)smem;                                   // [32][193]
  unsigned short* SB7 = (unsigned short*)(smem + 24704);      // [32][200]
  unsigned short* SH = (unsigned short*)(smem + 37504);       // [32][392]
  float* SZ = (float*)smem;                                   // [32][97]
  unsigned short* SM = (unsigned short*)(smem + 12416);       // [32][104]
  float* SMLP = (float*)(smem + 24704);                       // [32][97]

  const int tid = threadIdx.x;
  const int p0 = blockIdx.x * 32;
  const int b = p0 >> 12, pl0 = p0 & (Ln - 1);
  const int wv = tid >> 6, lane = tid & 63;
  const int l15 = lane & 15, lhi = lane >> 4;

  // --- 1. merge 4 direction buffers -> SY ---
  {
    const unsigned short* y0b = &yd[(size_t)(b * 4 + 0) * Ln * Din];
    const unsigned short* y1b = &yd[(size_t)(b * 4 + 1) * Ln * Din];
    const unsigned short* y2b = &yd[(size_t)(b * 4 + 2) * Ln * Din];
    const unsigned short* y3b = &yd[(size_t)(b * 4 + 3) * Ln * Din];
    for (int f = tid; f < 32 * 192; f += 256) {
      int pp = f / 192, d = f % 192;
      int p = pl0 + pp;
      int l1 = ((p & 63) << 6) | (p >> 6);
      SY[pp * 193 + d] = bf2f(y0b[(size_t)p * Din + d]) +
                         bf2f(y2b[(size_t)(Ln - 1 - p) * Din + d]) +
                         bf2f(y1b[(size_t)l1 * Din + d]) +
                         bf2f(y3b[(size_t)(Ln - 1 - l1) * Din + d]);
    }
  }
  __syncthreads();

  // --- 2. LN(192) -> SB7 (bf16) ---
  {
    const int pp = tid >> 3, t8 = tid & 7;
    float s = 0.f;
    for (int d2 = t8 * 24; d2 < t8 * 24 + 24; ++d2) s += SY[pp * 193 + d2];
    s += __shfl_xor(s, 1, 8); s += __shfl_xor(s, 2, 8); s += __shfl_xor(s, 4, 8);
    float m = s * (1.f / 192.f);
    float v = 0.f;
    for (int d2 = t8 * 24; d2 < t8 * 24 + 24; ++d2) {
      float t = SY[pp * 193 + d2] - m; v += t * t;
    }
    v += __shfl_xor(v, 1, 8); v += __shfl_xor(v, 2, 8); v += __shfl_xor(v, 4, 8);
    float rs = rsqrtf(v * (1.f / 192.f) + 1e-5f);
    for (int d2 = t8 * 24; d2 < t8 * 24 + 24; ++d2)
      SB7[pp * 200 + d2] = f2bf((SY[pp * 193 + d2] - m) * rs * gam[d2] + bet[d2]);
  }
  __syncthreads();

  // --- 3. out_proj MFMA (K=192) -> SZ (overwrites SY region; SY dead) ---
  for (int tt = wv; tt < 12; tt += 4) {   // 2 m x 6 n tiles
    const int mt = tt & 1, c0 = (tt >> 1) * 16;
    f32x4 acc = {0.f, 0.f, 0.f, 0.f};
#pragma unroll
    for (int kk = 0; kk < 6; ++kk) {
      short8 av = *reinterpret_cast<const short8*>(
          &SB7[(16 * mt + l15) * 200 + kk * 32 + lhi * 8]);
      short8 bv = *reinterpret_cast<const short8*>(
          &woutb[(size_t)(c0 + l15) * 192 + kk * 32 + lhi * 8]);
      acc = __builtin_amdgcn_mfma_f32_16x16x32_bf16(av, bv, acc, 0, 0, 0);
    }
    const int c = c0 + l15;
#pragma unroll
    for (int r = 0; r < 4; ++r) {
      int px = 16 * mt + lhi * 4 + r;
      SZ[px * 97 + c] = acc[r];
    }
  }
  __syncthreads();

  // --- 4. z = proj + x (in place, coalesced) ---
  for (int f = tid; f < 32 * 96; f += 256) {
    int pp = f / 96, c = f % 96;
    SZ[pp * 97 + c] += x[((size_t)b * Cn + c) * Ln + pl0 + pp];
  }
  __syncthreads();

  // --- 5. LN(96) on z -> SM (bf16) ---
  {
    const int pp = tid >> 3, t8 = tid & 7;
    float s = 0.f;
    for (int c = t8 * 12; c < t8 * 12 + 12; ++c) s += SZ[pp * 97 + c];
    s += __shfl_xor(s, 1, 8); s += __shfl_xor(s, 2, 8); s += __shfl_xor(s, 4, 8);
    float m = s * (1.f / 96.f);
    float v = 0.f;
    for (int c = t8 * 12; c < t8 * 12 + 12; ++c) {
      float t = SZ[pp * 97 + c] - m; v += t * t;
    }
    v += __shfl_xor(v, 1, 8); v += __shfl_xor(v, 2, 8); v += __shfl_xor(v, 4, 8);
    float rs = rsqrtf(v * (1.f / 96.f) + 1e-5f);
    for (int c = t8 * 12; c < t8 * 12 + 12; ++c)
      SM[pp * 104 + c] = f2bf((SZ[pp * 97 + c] - m) * rs * g2[c] + b2[c]);
  }
  __syncthreads();

  // --- 6. fc1 MFMA (K=96) + gelu -> SH (bf16) ---
  {
    const int mt = wv & 1;
    const int ngrp = (wv >> 1) * 12;
    for (int t = 0; t < 12; ++t) {
      const int n0 = (ngrp + t) * 16;
      f32x4 acc = {0.f, 0.f, 0.f, 0.f};
#pragma unroll
      for (int kk = 0; kk < 3; ++kk) {
        short8 av = *reinterpret_cast<const short8*>(
            &SM[(16 * mt + l15) * 104 + kk * 32 + lhi * 8]);
        short8 bv = *reinterpret_cast<const short8*>(
            &w1b[(size_t)(n0 + l15) * 96 + kk * 32 + lhi * 8]);
        acc = __builtin_amdgcn_mfma_f32_16x16x32_bf16(av, bv, acc, 0, 0, 0);
      }
      const int j = n0 + l15;
      const float bj = b1f[j];
#pragma unroll
      for (int r = 0; r < 4; ++r) {
        int px = 16 * mt + lhi * 4 + r;
        SH[px * 392 + j] = f2bf(geluf_(acc[r] + bj));
      }
    }
  }
  __syncthreads();

  // --- 7. fc2 MFMA (K=384) -> SMLP (overwrites SB7 region; SB7 dead) ---
  for (int tt = wv; tt < 12; tt += 4) {
    const int mt = tt & 1, c0 = (tt >> 1) * 16;
    f32x4 acc = {0.f, 0.f, 0.f, 0.f};
#pragma unroll
    for (int kk = 0; kk < 12; ++kk) {
      short8 av = *reinterpret_cast<const short8*>(
          &SH[(16 * mt + l15) * 392 + kk * 32 + lhi * 8]);
      short8 bv = *reinterpret_cast<const short8*>(
          &w2b[(size_t)(c0 + l15) * 384 + kk * 32 + lhi * 8]);
      acc = __builtin_amdgcn_mfma_f32_16x16x32_bf16(av, bv, acc, 0, 0, 0);
    }
    const int c = c0 + l15;
    const float bc = b2f[c];
#pragma unroll
    for (int r = 0; r < 4; ++r) {
      int px = 16 * mt + lhi * 4 + r;
      SMLP[px * 97 + c] = acc[r] + bc;
    }
  }
  __syncthreads();

  // --- 8. out = x + z + mlp (coalesced) ---
  for (int f = tid; f < 32 * 96; f += 256) {
    int c = f >> 5, pp = f & 31;
    size_t xi = ((size_t)b * Cn + c) * Ln + pl0 + pp;
    out[xi] = x[xi] + SZ[pp * 97 + c] + SMLP[pp * 97 + c];
  }
}

}  // namespace

extern "C" void kernel_launch(void* const* d_in, const int* in_sizes, int n_in,
                              void* d_out, int out_size, void* d_ws,
                              size_t ws_size, hipStream_t stream) {
  const float* x        = (const float*)d_in[0];
  const float* norm1_g  = (const float*)d_in[1];
  const float* norm1_b  = (const float*)d_in[2];
  const float* in_proj  = (const float*)d_in[3];
  const float* conv_w   = (const float*)d_in[4];
  const float* x_proj   = (const float*)d_in[5];
  const float* dt_w     = (const float*)d_in[6];
  const float* dt_b     = (const float*)d_in[7];
  const float* A_logs   = (const float*)d_in[8];
  const float* Ds       = (const float*)d_in[9];
  const float* onorm_g  = (const float*)d_in[10];
  const float* onorm_b  = (const float*)d_in[11];
  const float* out_proj = (const float*)d_in[12];
  const float* norm2_g  = (const float*)d_in[13];
  const float* norm2_b  = (const float*)d_in[14];
  const float* fc1_w    = (const float*)d_in[15];
  const float* fc1_b    = (const float*)d_in[16];
  const float* fc2_w    = (const float*)d_in[17];
  const float* fc2_b    = (const float*)d_in[18];
  float* out = (float*)d_out;

  float* ws = (float*)d_ws;
  size_t o = 0;
  float* dblp = ws + o; o += (size_t)Bn * Ln * 32;               // f32 2.1MB
  float* apb  = ws + o; o += (size_t)Bn * Kn * NCH * Din;
  float* heb  = ws + o; o += (size_t)Bn * Kn * NCH * Din;
  float* cin  = ws + o; o += (size_t)Bn * Kn * NCH * Din;
  unsigned short* ucpb = (unsigned short*)(ws + o); o += (size_t)Bn * Din * Ln / 2;     // bf16 6.3MB
  unsigned short* utb  = (unsigned short*)(ws + o); o += (size_t)Bn * Ln * Din / 2;     // bf16 6.3MB
  unsigned short* yd   = (unsigned short*)(ws + o); o += (size_t)Bn * Kn * Ln * Din / 2;// bf16 25MB
  unsigned short* w1b = (unsigned short*)(ws + o); o += 36864 / 2;
  unsigned short* w2b = (unsigned short*)(ws + o); o += 36864 / 2;
  unsigned short* winb = (unsigned short*)(ws + o); o += 18432 / 2;
  unsigned short* woutb = (unsigned short*)(ws + o); o += 18432 / 2;
  unsigned short* wxpb = (unsigned short*)(ws + o); o += 6144 / 2;

  kc_cvt<<<456, 256, 0, stream>>>(fc1_w, fc2_w, in_proj, out_proj, x_proj,
                                  w1b, w2b, winb, woutb, wxpb);
  k1_ln_inproj<<<512, 256, 0, stream>>>(x, norm1_g, norm1_b, winb, ucpb);
  k2a_conv<<<Bn * Hn * 2, 512, 0, stream>>>(ucpb, conv_w, utb);
  k2b_xproj<<<512, 256, 0, stream>>>(utb, wxpb, dblp);
  k4_scan1<<<Bn * Kn * NCH, 192, 0, stream>>>(utb, dblp, dt_w, dt_b, A_logs,
                                              apb, heb);
  k5_carry<<<12, 256, 0, stream>>>(apb, heb, cin);
  k6_scan2<<<Bn * Kn * NCH, 192, 0, stream>>>(utb, dblp, dt_w, dt_b, A_logs,
                                              Ds, cin, yd);
  k78_tail<<<512, 256, 0, stream>>>(yd, onorm_g, onorm_b, woutb, norm2_g,
                                    norm2_b, w1b, fc1_b, w2b, fc2_b, x, out);
}